// Round 11
// baseline (410.182 us; speedup 1.0000x reference)
//
#include <hip/hip_runtime.h>
#include <math.h>

#define NNODES 50000
#define NEDGES 800000
#define BN_EPS 1e-5f
#define DEGC 128   // LDS-cached in-edges per node; fallback path beyond
#define NB 391     // buckets (128 nodes each; last has 80)
#define NPB 128
#define SCG 256    // scatter blocks (chunked)
#define HWG 192    // histogram blocks inside histwt
#define NSH 32     // bn-stats shadow copies (atomic contention spread)

typedef unsigned int uint;
typedef unsigned short ushort;
typedef __attribute__((ext_vector_type(8))) short bf16x8;
typedef __attribute__((ext_vector_type(4))) float f32x4;

// fp32 -> bf16 (RNE)
static __device__ __forceinline__ ushort f2bf(float f) {
    uint u = __float_as_uint(f);
    return (ushort)((u + 0x7fffu + ((u >> 16) & 1u)) >> 16);
}
static __device__ __forceinline__ float bfhi(ushort h) {
    return __uint_as_float((uint)h << 16);
}
// 2 packed bf16 -> 2 fp32 (elem0 = low 16 bits)
static __device__ __forceinline__ float2 bf2f(uint v) {
    float2 r;
    r.x = __uint_as_float(v << 16);
    r.y = __uint_as_float(v & 0xffff0000u);
    return r;
}
// fp32 -> (hi, lo) bf16 split: v ~= hi + lo with |err| ~ 2^-17 |v|
static __device__ __forceinline__ void splitbf(float v, ushort& h, ushort& l) {
    h = f2bf(v);
    l = f2bf(v - bfhi(h));
}

// ============ fused: bucket histogram (blocks 0..HWG-1) + W transpose/split ============
__global__ __launch_bounds__(256) void histwt(const int* __restrict__ dst,
                                              int* __restrict__ bcnt,
                                              const float* __restrict__ W1,
                                              const float* __restrict__ W2,
                                              const float* __restrict__ W3,
                                              ushort* __restrict__ wt1h, ushort* __restrict__ wt1l,
                                              ushort* __restrict__ wt2h, ushort* __restrict__ wt2l,
                                              ushort* __restrict__ wt3h, ushort* __restrict__ wt3l) {
    if (blockIdx.x < HWG) {
        __shared__ int h[NB];
        for (int i = threadIdx.x; i < NB; i += 256) h[i] = 0;
        __syncthreads();
        for (int e = blockIdx.x * 256 + threadIdx.x; e < NEDGES; e += HWG * 256)
            atomicAdd(&h[dst[e] >> 7], 1);
        __syncthreads();
        for (int i = threadIdx.x; i < NB; i += 256)
            if (h[i]) atomicAdd(&bcnt[i], h[i]);
    } else {
        int idx = (blockIdx.x - HWG) * 256 + threadIdx.x;  // 144*256 = 36864
        ushort h, l;
        if (idx < 16384) {  // W1 128x128
            int k = idx >> 7, c = idx & 127;
            splitbf(W1[idx], h, l);
            wt1h[c * 128 + k] = h; wt1l[c * 128 + k] = l;
        } else if (idx < 32768) {  // W2 128x128
            int i = idx - 16384;
            int k = i >> 7, c = i & 127;
            splitbf(W2[i], h, l);
            wt2h[c * 128 + k] = h; wt2l[c * 128 + k] = l;
        } else {  // W3 128x32
            int i = idx - 32768;
            int k = i >> 5, c = i & 31;
            splitbf(W3[i], h, l);
            wt3h[c * 128 + k] = h; wt3l[c * 128 + k] = l;
        }
    }
}

// scan over buckets (+ fused atilde: atl[0..31]=W5@as5, atl[32..63]=W5@ad5)
__global__ void bucket_scan(const int* __restrict__ bcnt, int* __restrict__ eoff,
                            int* __restrict__ boff, int* __restrict__ ecur,
                            int* __restrict__ off, const float* __restrict__ W5,
                            const float* __restrict__ as5, const float* __restrict__ ad5,
                            float* __restrict__ atl) {
    __shared__ int w1[8], w2[8];
    int t = threadIdx.x, lane = t & 63, wv = t >> 6;  // 512 threads, 8 waves
    int v = (t < NB) ? bcnt[t] : 0;
    int nib = 0;
    if (t < NB) nib = (t == NB - 1) ? (NNODES - (NB - 1) * NPB) : NPB;
    int x1 = v, x2 = v + nib;
#pragma unroll
    for (int s = 1; s < 64; s <<= 1) {
        int t1 = __shfl_up(x1, s), t2 = __shfl_up(x2, s);
        if (lane >= s) { x1 += t1; x2 += t2; }
    }
    if (lane == 63) { w1[wv] = x1; w2[wv] = x2; }
    __syncthreads();
    if (wv == 0) {
        int a = (lane < 8) ? w1[lane] : 0, b = (lane < 8) ? w2[lane] : 0;
#pragma unroll
        for (int s = 1; s < 8; s <<= 1) {
            int ta = __shfl_up(a, s), tb = __shfl_up(b, s);
            if (lane >= s) { a += ta; b += tb; }
        }
        if (lane < 8) { w1[lane] = a; w2[lane] = b; }
    }
    __syncthreads();
    int p1 = (wv > 0) ? w1[wv - 1] : 0, p2 = (wv > 0) ? w2[wv - 1] : 0;
    x1 += p1; x2 += p2;
    if (t < NB) { eoff[t] = x1 - v; boff[t] = x2 - (v + nib); ecur[t] = 0; }
    if (t == NB - 1) { eoff[NB] = x1; boff[NB] = x2; off[NNODES] = x2; }
    if (t >= 448) {  // fused atilde
        int idx = t - 448;
        int k = idx & 31;
        const float* a = (idx < 32) ? as5 : ad5;
        float s = 0.f;
        for (int f = 0; f < 128; ++f) s += W5[k * 128 + f] * a[f];
        atl[idx] = s;
    }
}

// ===== fused: block-aggregated scatter (blocks 0..SCG-1) ∥ GAT1 split-MFMA =====
__global__ __launch_bounds__(256) void scatter_mm(const int* __restrict__ src,
                                                  const int* __restrict__ dst,
                                                  const int* __restrict__ eoff,
                                                  int* __restrict__ ecur,
                                                  uint* __restrict__ ebuf,
                                                  const float* __restrict__ X,
                                                  const ushort* __restrict__ Wth,
                                                  const ushort* __restrict__ Wtl,
                                                  const float* __restrict__ av_s,
                                                  const float* __restrict__ av_d,
                                                  ushort* __restrict__ Obf,
                                                  float* __restrict__ es,
                                                  float* __restrict__ ed, int N) {
    __shared__ int lh[NB];
    __shared__ int lcur[NB];
    __shared__ __align__(16) ushort sAh[64 * 136];
    __shared__ __align__(16) ushort sAl[64 * 136];
    int tid = threadIdx.x;
    if (blockIdx.x < SCG) {  // ---- scatter path ----
        const int CH = (NEDGES + SCG - 1) / SCG;
        int c0 = blockIdx.x * CH;
        int c1 = min(c0 + CH, NEDGES);
        for (int i = tid; i < NB; i += 256) { lh[i] = 0; lcur[i] = 0; }
        __syncthreads();
        for (int e = c0 + tid; e < c1; e += 256) atomicAdd(&lh[dst[e] >> 7], 1);
        __syncthreads();
        for (int i = tid; i < NB; i += 256) {
            int c = lh[i];
            lh[i] = c ? (eoff[i] + atomicAdd(&ecur[i], c)) : 0;
        }
        __syncthreads();
        for (int e = c0 + tid; e < c1; e += 256) {
            int d = dst[e];
            int bk = d >> 7;
            int p = lh[bk] + atomicAdd(&lcur[bk], 1);
            ebuf[p] = ((uint)(d & 127) << 16) | (uint)src[e];
        }
        return;
    }
    // ---- GAT1 mfma path (KK=128, WBF, no AFF) ----
    int rowBase = (int)(blockIdx.x - SCG) * 64;
    int lane = tid & 63, wv = tid >> 6;
    int lr = lane & 15, lq = lane >> 4;
#pragma unroll
    for (int j = 0; j < 8; ++j) {
        int idx = tid + j * 256;
        int row = idx >> 5;
        int cq = idx & 31;
        int gr = rowBase + row;
        float4 v = make_float4(0.f, 0.f, 0.f, 0.f);
        if (gr < N) v = *(const float4*)(X + (size_t)gr * 128 + cq * 4);
        ushort h0, h1, h2, h3, l0, l1, l2, l3;
        splitbf(v.x, h0, l0); splitbf(v.y, h1, l1);
        splitbf(v.z, h2, l2); splitbf(v.w, h3, l3);
        uint2 ph, pl;
        ph.x = (uint)h0 | ((uint)h1 << 16);
        ph.y = (uint)h2 | ((uint)h3 << 16);
        pl.x = (uint)l0 | ((uint)l1 << 16);
        pl.y = (uint)l2 | ((uint)l3 << 16);
        *(uint2*)&sAh[row * 136 + cq * 4] = ph;
        *(uint2*)&sAl[row * 136 + cq * 4] = pl;
    }
    __syncthreads();
    const int ncol0 = wv * 32;
    f32x4 acc[4][2];
#pragma unroll
    for (int mi = 0; mi < 4; ++mi)
#pragma unroll
        for (int ni = 0; ni < 2; ++ni) acc[mi][ni] = (f32x4){0.f, 0.f, 0.f, 0.f};
#pragma unroll
    for (int kq = 0; kq < 4; ++kq) {
        int kb = kq * 32 + lq * 8;
        bf16x8 ah[4], al[4], bh[2], bl[2];
#pragma unroll
        for (int mi = 0; mi < 4; ++mi) {
            ah[mi] = *(const bf16x8*)&sAh[(16 * mi + lr) * 136 + kb];
            al[mi] = *(const bf16x8*)&sAl[(16 * mi + lr) * 136 + kb];
        }
#pragma unroll
        for (int ni = 0; ni < 2; ++ni) {
            size_t bo = (size_t)(ncol0 + 16 * ni + lr) * 128 + kb;
            bh[ni] = *(const bf16x8*)(Wth + bo);
            bl[ni] = *(const bf16x8*)(Wtl + bo);
        }
#pragma unroll
        for (int mi = 0; mi < 4; ++mi)
#pragma unroll
            for (int ni = 0; ni < 2; ++ni) {
                acc[mi][ni] = __builtin_amdgcn_mfma_f32_16x16x32_bf16(
                    ah[mi], bh[ni], acc[mi][ni], 0, 0, 0);
                acc[mi][ni] = __builtin_amdgcn_mfma_f32_16x16x32_bf16(
                    al[mi], bh[ni], acc[mi][ni], 0, 0, 0);
                acc[mi][ni] = __builtin_amdgcn_mfma_f32_16x16x32_bf16(
                    ah[mi], bl[ni], acc[mi][ni], 0, 0, 0);
            }
    }
    {
        float as0 = av_s[ncol0 + lr], as1 = av_s[ncol0 + 16 + lr];
        float ad0 = av_d[ncol0 + lr], ad1 = av_d[ncol0 + 16 + lr];
#pragma unroll
        for (int mi = 0; mi < 4; ++mi)
#pragma unroll
            for (int r = 0; r < 4; ++r) {
                float ps = acc[mi][0][r] * as0 + acc[mi][1][r] * as1;
                float pd = acc[mi][0][r] * ad0 + acc[mi][1][r] * ad1;
#pragma unroll
                for (int s = 1; s < 16; s <<= 1) {
                    ps += __shfl_xor(ps, s);
                    pd += __shfl_xor(pd, s);
                }
                if (lr == 0) {
                    int gr = rowBase + 16 * mi + lq * 4 + r;
                    if (gr < N) {
                        es[(size_t)gr * 4 + wv] = ps;
                        ed[(size_t)gr * 4 + wv] = pd;
                    }
                }
            }
    }
    __syncthreads();
#pragma unroll
    for (int mi = 0; mi < 4; ++mi)
#pragma unroll
        for (int ni = 0; ni < 2; ++ni)
#pragma unroll
            for (int r = 0; r < 4; ++r)
                sAh[(16 * mi + lq * 4 + r) * 136 + ncol0 + 16 * ni + lr] =
                    f2bf(acc[mi][ni][r]);
    __syncthreads();
    int row = tid >> 2, c0 = (tid & 3) * 32;
    int gr = rowBase + row;
    if (gr < N) {
        uint4 o0 = *(const uint4*)&sAh[row * 136 + c0];
        uint4 o1 = *(const uint4*)&sAh[row * 136 + c0 + 8];
        uint4 o2 = *(const uint4*)&sAh[row * 136 + c0 + 16];
        uint4 o3 = *(const uint4*)&sAh[row * 136 + c0 + 24];
        uint4* d4 = (uint4*)(Obf + (size_t)gr * 128 + c0);
        d4[0] = o0; d4[1] = o1; d4[2] = o2; d4[3] = o3;
    }
}

__global__ __launch_bounds__(256) void bucket_place(const uint* __restrict__ ebuf,
                                                    const int* __restrict__ eoff,
                                                    const int* __restrict__ boff,
                                                    int* __restrict__ off,
                                                    int* __restrict__ ssorted) {
    __shared__ int cnt[NPB];
    __shared__ int cur[NPB];
    __shared__ int wtot[2];
    int b = blockIdx.x;
    int nib = (b == NB - 1) ? (NNODES - (NB - 1) * NPB) : NPB;
    int t = threadIdx.x;
    for (int i = t; i < NPB; i += 256) { cnt[i] = 0; cur[i] = 0; }
    __syncthreads();
    int e0 = eoff[b], e1 = eoff[b + 1];
    for (int i = e0 + t; i < e1; i += 256) atomicAdd(&cnt[ebuf[i] >> 16], 1);
    __syncthreads();
    int lane = t & 63, wv = t >> 6;
    int deg = (t < nib) ? cnt[t] + 1 : 0;  // +1 self-loop
    int x = deg;
#pragma unroll
    for (int s = 1; s < 64; s <<= 1) {
        int tv = __shfl_up(x, s);
        if (lane >= s) x += tv;
    }
    if (lane == 63 && wv < 2) wtot[wv] = x;
    __syncthreads();
    int excl = x - deg + ((wv == 1) ? wtot[0] : 0);
    if (t < nib) {
        int base = boff[b] + excl;
        off[b * NPB + t] = base;
        cnt[t] = excl;
        ssorted[base + deg - 1] = b * NPB + t;
    }
    __syncthreads();
    int bb = boff[b];
    for (int i = e0 + t; i < e1; i += 256) {
        uint v = ebuf[i];
        int ld = v >> 16;
        int pos = bb + cnt[ld] + atomicAdd(&cur[ld], 1);
        ssorted[pos] = (int)(v & 0xffffu);
    }
}

// ===== split-bf16 MFMA projection: O = (AFF? bn(X) : X) @ W, fused attn scores =====
template <int KK, bool WBF, bool AFF>
__global__ __launch_bounds__(256) void mfma_mm(const float* __restrict__ X,
                                               const ushort* __restrict__ Wth,
                                               const ushort* __restrict__ Wtl,
                                               const float* __restrict__ bnsums,
                                               const float* __restrict__ bng,
                                               const float* __restrict__ bnbe,
                                               const float* __restrict__ av_s,
                                               const float* __restrict__ av_d,
                                               float* __restrict__ Of,
                                               ushort* __restrict__ Obf,
                                               float* __restrict__ es,
                                               float* __restrict__ ed,
                                               int N, float inv_n) {
    constexpr int KQ = KK / 32;
    constexpr int MI = WBF ? 4 : 1;
    __shared__ __align__(16) ushort sAh[64 * 136];
    __shared__ __align__(16) ushort sAl[64 * 136];
    __shared__ float sSc[128], sSh[128];
    int tid = threadIdx.x;
    int rowBase = blockIdx.x * 64;
    int lane = tid & 63, wv = tid >> 6;
    int lr = lane & 15, lq = lane >> 4;

    if constexpr (AFF) {  // consumer-side bn finalization from shadowed sums
        if (tid < KK) {
            float su = 0.f, sq = 0.f;
#pragma unroll 4
            for (int sh = 0; sh < NSH; ++sh) {
                su += bnsums[sh * 256 + tid];
                sq += bnsums[sh * 256 + 128 + tid];
            }
            float mu = su * inv_n;
            float var = sq * inv_n - mu * mu;
            float s = bng[tid] * rsqrtf(var + BN_EPS);
            sSc[tid] = s;
            sSh[tid] = fmaf(-mu, s, bnbe[tid]);
        }
        __syncthreads();
    }

    // ---- A: 64 x KK fp32 -> hi/lo bf16 LDS ----
#pragma unroll
    for (int j = 0; j < 64 * KK / 4 / 256; ++j) {
        int idx = tid + j * 256;
        int row = idx / (KK / 4);
        int cq = idx - row * (KK / 4);
        int gr = rowBase + row;
        float4 v = make_float4(0.f, 0.f, 0.f, 0.f);
        if (gr < N) {
            v = *(const float4*)(X + (size_t)gr * KK + cq * 4);
            if constexpr (AFF) {
                int c = cq * 4;
                v.x = fmaf(v.x, sSc[c], sSh[c]);
                v.y = fmaf(v.y, sSc[c + 1], sSh[c + 1]);
                v.z = fmaf(v.z, sSc[c + 2], sSh[c + 2]);
                v.w = fmaf(v.w, sSc[c + 3], sSh[c + 3]);
            }
        }
        ushort h0, h1, h2, h3, l0, l1, l2, l3;
        splitbf(v.x, h0, l0); splitbf(v.y, h1, l1);
        splitbf(v.z, h2, l2); splitbf(v.w, h3, l3);
        uint2 ph, pl;
        ph.x = (uint)h0 | ((uint)h1 << 16);
        ph.y = (uint)h2 | ((uint)h3 << 16);
        pl.x = (uint)l0 | ((uint)l1 << 16);
        pl.y = (uint)l2 | ((uint)l3 << 16);
        *(uint2*)&sAh[row * 136 + cq * 4] = ph;
        *(uint2*)&sAl[row * 136 + cq * 4] = pl;
    }
    __syncthreads();

    const int mrow0 = WBF ? 0 : wv * 16;
    const int ncol0 = WBF ? wv * 32 : 0;
    f32x4 acc[MI][2];
#pragma unroll
    for (int mi = 0; mi < MI; ++mi)
#pragma unroll
        for (int ni = 0; ni < 2; ++ni) acc[mi][ni] = (f32x4){0.f, 0.f, 0.f, 0.f};

#pragma unroll
    for (int kq = 0; kq < KQ; ++kq) {
        int kb = kq * 32 + lq * 8;
        bf16x8 ah[MI], al[MI], bh[2], bl[2];
#pragma unroll
        for (int mi = 0; mi < MI; ++mi) {
            ah[mi] = *(const bf16x8*)&sAh[(mrow0 + 16 * mi + lr) * 136 + kb];
            al[mi] = *(const bf16x8*)&sAl[(mrow0 + 16 * mi + lr) * 136 + kb];
        }
#pragma unroll
        for (int ni = 0; ni < 2; ++ni) {
            size_t bo = (size_t)(ncol0 + 16 * ni + lr) * KK + kb;
            bh[ni] = *(const bf16x8*)(Wth + bo);
            bl[ni] = *(const bf16x8*)(Wtl + bo);
        }
#pragma unroll
        for (int mi = 0; mi < MI; ++mi)
#pragma unroll
            for (int ni = 0; ni < 2; ++ni) {
                acc[mi][ni] = __builtin_amdgcn_mfma_f32_16x16x32_bf16(
                    ah[mi], bh[ni], acc[mi][ni], 0, 0, 0);
                acc[mi][ni] = __builtin_amdgcn_mfma_f32_16x16x32_bf16(
                    al[mi], bh[ni], acc[mi][ni], 0, 0, 0);
                acc[mi][ni] = __builtin_amdgcn_mfma_f32_16x16x32_bf16(
                    ah[mi], bl[ni], acc[mi][ni], 0, 0, 0);
            }
    }

    // ---- es/ed from fp32 accumulators ----
    {
        float as0 = av_s[ncol0 + lr], as1 = av_s[ncol0 + 16 + lr];
        float ad0 = av_d[ncol0 + lr], ad1 = av_d[ncol0 + 16 + lr];
#pragma unroll
        for (int mi = 0; mi < MI; ++mi)
#pragma unroll
            for (int r = 0; r < 4; ++r) {
                float ps = acc[mi][0][r] * as0 + acc[mi][1][r] * as1;
                float pd = acc[mi][0][r] * ad0 + acc[mi][1][r] * ad1;
#pragma unroll
                for (int s = 1; s < 16; s <<= 1) {
                    ps += __shfl_xor(ps, s);
                    pd += __shfl_xor(pd, s);
                }
                if (lr == 0) {
                    int gr = rowBase + mrow0 + 16 * mi + lq * 4 + r;
                    if (gr < N) {
                        if constexpr (WBF) {
                            es[(size_t)gr * 4 + wv] = ps;
                            ed[(size_t)gr * 4 + wv] = pd;
                        } else {
                            es[gr] = ps;
                            ed[gr] = pd;
                        }
                    }
                }
            }
    }
    __syncthreads();  // fragment reads done; sAh reusable

    if constexpr (WBF) {
#pragma unroll
        for (int mi = 0; mi < MI; ++mi)
#pragma unroll
            for (int ni = 0; ni < 2; ++ni)
#pragma unroll
                for (int r = 0; r < 4; ++r)
                    sAh[(16 * mi + lq * 4 + r) * 136 + ncol0 + 16 * ni + lr] =
                        f2bf(acc[mi][ni][r]);
        __syncthreads();
        int row = tid >> 2, c0 = (tid & 3) * 32;
        int gr = rowBase + row;
        if (gr < N) {
            uint4 o0 = *(const uint4*)&sAh[row * 136 + c0];
            uint4 o1 = *(const uint4*)&sAh[row * 136 + c0 + 8];
            uint4 o2 = *(const uint4*)&sAh[row * 136 + c0 + 16];
            uint4 o3 = *(const uint4*)&sAh[row * 136 + c0 + 24];
            uint4* d4 = (uint4*)(Obf + (size_t)gr * 128 + c0);
            d4[0] = o0; d4[1] = o1; d4[2] = o2; d4[3] = o3;
        }
    } else {
        float* sOutF = (float*)sAh;  // [64][36] fp32
#pragma unroll
        for (int ni = 0; ni < 2; ++ni)
#pragma unroll
            for (int r = 0; r < 4; ++r)
                sOutF[(mrow0 + lq * 4 + r) * 36 + 16 * ni + lr] = acc[0][ni][r];
        __syncthreads();
        int row = tid >> 2, c0 = (tid & 3) * 8;
        int gr = rowBase + row;
        if (gr < N) {
            float4 v0 = *(const float4*)&sOutF[row * 36 + c0];
            float4 v1 = *(const float4*)&sOutF[row * 36 + c0 + 4];
            *(float4*)(Of + (size_t)gr * 32 + c0) = v0;
            *(float4*)(Of + (size_t)gr * 32 + c0 + 4) = v1;
        }
    }
}

// ====== gather softmax-aggregate, F=128, 4 heads, h in bf16, fused bn-stats ======
// Phase 1: wave-parallel scores; phase 2: uint4 row gather, 16-edge main loop
// (4 outstanding uint4 loads/lane = 64B in flight). No mid barrier.
__global__ __launch_bounds__(256) void node_agg_bf4(const int* __restrict__ off,
                                                    const int* __restrict__ ssorted,
                                                    const ushort* __restrict__ Hb,
                                                    const float* __restrict__ es,
                                                    const float* __restrict__ ed,
                                                    const float* __restrict__ bias,
                                                    float* __restrict__ outp,
                                                    float* __restrict__ sums) {
    __shared__ float lds_ex[4][DEGC * 4];
    __shared__ int lds_s[4][DEGC];
    __shared__ float red_v[4][128];
    __shared__ float red_q[4][128];
    int wib = threadIdx.x >> 6;
    int lane = threadIdx.x & 63;
    int d = blockIdx.x * 4 + wib;
    int beg = off[d], end = off[d + 1];
    int m = end - beg;  // >= 1

    // ---- phase 1: scores (wave-parallel over edges x heads) ----
    int lh = lane & 3, le = lane >> 2;
    float edl = ed[(size_t)d * 4 + lh];
    float denp = 0.f;
    for (int base = 0; base < m; base += 16) {
        int e = base + le;
        if (e < m) {
            int s = ssorted[beg + e];
            if (lh == 0 && e < DEGC) lds_s[wib][e] = s;
            float a = es[(size_t)s * 4 + lh] + edl;
            a = a > 0.f ? a : 0.2f * a;
            float ex = __expf(a);
            denp += ex;
            if (e < DEGC) lds_ex[wib][e * 4 + lh] = ex;
        }
    }
#pragma unroll
    for (int sft = 4; sft < 64; sft <<= 1) denp += __shfl_xor(denp, sft);
    float inv = 1.f / denp;  // per-lane: inverse denom of head lh
    int mu = m < DEGC ? m : DEGC;
    // premultiply (idx & 3 == lh for stride-64 walk -> lane's own inv applies)
    for (int idx = lane; idx < mu * 4; idx += 64) lds_ex[wib][idx] *= inv;

    // ---- phase 2: uint4 weighted row gather ----
    const uint4* Hu4 = (const uint4*)Hb;  // 16 uint4 per 128-bf16 row
    int sub = lane >> 4, fl = lane & 15;  // edge subset, feature quad [8fl,8fl+8)
    int head = fl >> 2;
    float inv2 = __shfl(inv, head);  // fallback path only
    float edl2 = __shfl(edl, head);
    float acc[8];
#pragma unroll
    for (int k = 0; k < 8; ++k) acc[k] = 0.f;

    auto accum = [&](uint4 v, float w) {
        float2 f;
        f = bf2f(v.x); acc[0] += w * f.x; acc[1] += w * f.y;
        f = bf2f(v.y); acc[2] += w * f.x; acc[3] += w * f.y;
        f = bf2f(v.z); acc[4] += w * f.x; acc[5] += w * f.y;
        f = bf2f(v.w); acc[6] += w * f.x; acc[7] += w * f.y;
    };

    int i = 0;
    for (; i + 16 <= mu; i += 16) {  // 4 edges per lane per iter
        int e0 = i + sub, e1 = e0 + 4, e2 = e0 + 8, e3 = e0 + 12;
        int s0 = lds_s[wib][e0], s1 = lds_s[wib][e1];
        int s2 = lds_s[wib][e2], s3 = lds_s[wib][e3];
        float w0 = lds_ex[wib][e0 * 4 + head];
        float w1 = lds_ex[wib][e1 * 4 + head];
        float w2 = lds_ex[wib][e2 * 4 + head];
        float w3 = lds_ex[wib][e3 * 4 + head];
        uint4 v0 = Hu4[(size_t)s0 * 16 + fl];
        uint4 v1 = Hu4[(size_t)s1 * 16 + fl];
        uint4 v2 = Hu4[(size_t)s2 * 16 + fl];
        uint4 v3 = Hu4[(size_t)s3 * 16 + fl];
        accum(v0, w0);
        accum(v1, w1);
        accum(v2, w2);
        accum(v3, w3);
    }
    for (; i + 8 <= mu; i += 8) {  // 2 edges per lane
        int e0 = i + sub, e1 = e0 + 4;
        int s0 = lds_s[wib][e0], s1 = lds_s[wib][e1];
        float w0 = lds_ex[wib][e0 * 4 + head];
        float w1 = lds_ex[wib][e1 * 4 + head];
        uint4 v0 = Hu4[(size_t)s0 * 16 + fl];
        uint4 v1 = Hu4[(size_t)s1 * 16 + fl];
        accum(v0, w0);
        accum(v1, w1);
    }
    for (; i + 4 <= mu; i += 4) {
        int e = i + sub;
        int s = lds_s[wib][e];
        float w = lds_ex[wib][e * 4 + head];
        uint4 v = Hu4[(size_t)s * 16 + fl];
        accum(v, w);
    }
    if (i + sub < mu) {  // tail (<4 edges)
        int e = i + sub;
        int s = lds_s[wib][e];
        float w = lds_ex[wib][e * 4 + head];
        uint4 v = Hu4[(size_t)s * 16 + fl];
        accum(v, w);
    }
    for (int e = mu + sub; e < m; e += 4) {  // rare high-degree fallback
        int s = ssorted[beg + e];
        float a = es[(size_t)s * 4 + head] + edl2;
        a = a > 0.f ? a : 0.2f * a;
        float w = __expf(a) * inv2;
        uint4 v = Hu4[(size_t)s * 16 + fl];
        accum(v, w);
    }
    // combine the 4 edge subsets
#pragma unroll
    for (int k = 0; k < 8; ++k) {
        acc[k] += __shfl_xor(acc[k], 16);
        acc[k] += __shfl_xor(acc[k], 32);
    }
    if (sub == 0) {  // 16 lanes cover the 128-feature row, 32B each
        int c = fl * 8;
        float v[8];
#pragma unroll
        for (int k = 0; k < 8; ++k) v[k] = fmaxf(acc[k] + bias[c + k], 0.f);
        *(float4*)(outp + (size_t)d * 128 + c) = make_float4(v[0], v[1], v[2], v[3]);
        *(float4*)(outp + (size_t)d * 128 + c + 4) = make_float4(v[4], v[5], v[6], v[7]);
#pragma unroll
        for (int k = 0; k < 8; ++k) {
            red_v[wib][c + k] = v[k];
            red_q[wib][c + k] = v[k] * v[k];
        }
    }
    __syncthreads();
    // ---- fused bn stats: per-block reduce -> shadowed atomics ----
    int t = threadIdx.x;
    int sh = (blockIdx.x & (NSH - 1)) * 256;
    if (t < 128) {
        float s = red_v[0][t] + red_v[1][t] + red_v[2][t] + red_v[3][t];
        atomicAdd(&sums[sh + t], s);
    } else {
        int u = t - 128;
        float q = red_q[0][u] + red_q[1][u] + red_q[2][u] + red_q[3][u];
        atomicAdd(&sums[sh + 128 + u], q);
    }
}

// ====== gather softmax-aggregate F=32 fp32, fused bn-stats (GAT4 agg) ======
// 2 nodes/wave; phase 2 widened: lane = (edge-subset sub=g>>3, quad q=g&7),
// float4 row loads, 16-edge main loop (4 outstanding float4/lane). Subset
// partials combined via xor 8,16 (group-local).
__global__ __launch_bounds__(256) void node_agg_f32s(const int* __restrict__ off,
                                                     const int* __restrict__ ssorted,
                                                     const float* __restrict__ Hb,
                                                     const float* __restrict__ es,
                                                     const float* __restrict__ ed,
                                                     const float* __restrict__ bias,
                                                     float* __restrict__ outp,
                                                     float* __restrict__ sums) {
    __shared__ float lds_ex[8][DEGC];
    __shared__ int lds_s[8][DEGC];
    __shared__ float red_v[8][32];
    __shared__ float red_q[8][32];
    int tid = threadIdx.x;
    int wib = tid >> 6, lane = tid & 63;
    int grp = lane >> 5, g = lane & 31;
    int nn = wib * 2 + grp;
    int d = blockIdx.x * 8 + nn;
    int beg = off[d], end = off[d + 1];
    int m = end - beg;

    float edv = ed[d];
    float denp = 0.f;
    for (int base = 0; base < m; base += 32) {
        int e = base + g;
        if (e < m) {
            int s = ssorted[beg + e];
            if (e < DEGC) lds_s[nn][e] = s;
            float a = es[s] + edv;
            a = a > 0.f ? a : 0.2f * a;
            float ex = __expf(a);
            denp += ex;
            if (e < DEGC) lds_ex[nn][e] = ex;
        }
    }
#pragma unroll
    for (int sft = 1; sft < 32; sft <<= 1) denp += __shfl_xor(denp, sft);
    int mu = m < DEGC ? m : DEGC;
    float inv = 1.f / denp;
    for (int idx = g; idx < mu; idx += 32) lds_ex[nn][idx] *= inv;  // premult

    const float4* Hf4 = (const float4*)Hb;  // 8 float4 per 32-f row
    int sub = g >> 3, q = g & 7;            // edge subset, feature quad [4q,4q+4)
    float acc[4] = {0.f, 0.f, 0.f, 0.f};
    auto accum = [&](float4 v, float w) {
        acc[0] += w * v.x; acc[1] += w * v.y; acc[2] += w * v.z; acc[3] += w * v.w;
    };
    int i = 0;
    for (; i + 16 <= mu; i += 16) {  // 4 edges/lane
        int e0 = i + sub, e1 = e0 + 4, e2 = e0 + 8, e3 = e0 + 12;
        int s0 = lds_s[nn][e0], s1 = lds_s[nn][e1];
        int s2 = lds_s[nn][e2], s3 = lds_s[nn][e3];
        float w0 = lds_ex[nn][e0], w1 = lds_ex[nn][e1];
        float w2 = lds_ex[nn][e2], w3 = lds_ex[nn][e3];
        float4 v0 = Hf4[(size_t)s0 * 8 + q];
        float4 v1 = Hf4[(size_t)s1 * 8 + q];
        float4 v2 = Hf4[(size_t)s2 * 8 + q];
        float4 v3 = Hf4[(size_t)s3 * 8 + q];
        accum(v0, w0); accum(v1, w1); accum(v2, w2); accum(v3, w3);
    }
    for (; i + 8 <= mu; i += 8) {
        int e0 = i + sub, e1 = e0 + 4;
        int s0 = lds_s[nn][e0], s1 = lds_s[nn][e1];
        float w0 = lds_ex[nn][e0], w1 = lds_ex[nn][e1];
        float4 v0 = Hf4[(size_t)s0 * 8 + q];
        float4 v1 = Hf4[(size_t)s1 * 8 + q];
        accum(v0, w0); accum(v1, w1);
    }
    for (; i + 4 <= mu; i += 4) {
        int e = i + sub;
        accum(Hf4[(size_t)lds_s[nn][e] * 8 + q], lds_ex[nn][e]);
    }
    if (i + sub < mu) {
        int e = i + sub;
        accum(Hf4[(size_t)lds_s[nn][e] * 8 + q], lds_ex[nn][e]);
    }
    for (int e = mu + sub; e < m; e += 4) {  // rare high-degree fallback
        int s = ssorted[beg + e];
        float a = es[s] + edv;
        a = a > 0.f ? a : 0.2f * a;
        accum(Hf4[(size_t)s * 8 + q], __expf(a) * inv);
    }
#pragma unroll
    for (int k = 0; k < 4; ++k) {
        acc[k] += __shfl_xor(acc[k], 8);
        acc[k] += __shfl_xor(acc[k], 16);
    }
    if (sub == 0) {  // 8 lanes cover 32 features
        int c = q * 4;
        float v[4];
#pragma unroll
        for (int k = 0; k < 4; ++k) v[k] = fmaxf(acc[k] + bias[c + k], 0.f);
        *(float4*)(outp + (size_t)d * 32 + c) = make_float4(v[0], v[1], v[2], v[3]);
#pragma unroll
        for (int k = 0; k < 4; ++k) {
            red_v[nn][c + k] = v[k];
            red_q[nn][c + k] = v[k] * v[k];
        }
    }
    __syncthreads();
    int sh = (blockIdx.x & (NSH - 1)) * 64;
    if (tid < 32) {
        float s = 0.f;
#pragma unroll
        for (int k = 0; k < 8; ++k) s += red_v[k][tid];
        atomicAdd(&sums[sh + tid], s);
    } else if (tid < 64) {
        int u = tid - 32;
        float q2 = 0.f;
#pragma unroll
        for (int k = 0; k < 8; ++k) q2 += red_q[k][u];
        atomicAdd(&sums[sh + 32 + u], q2);
    }
}

// ====== fused: GAT3 aggregate (relu, +b3) -> x4; h4 = x4 @ W4; es4/ed4 ======
// 2 nodes/wave; float4-widened gather; sW staged, barrier right after.
__global__ __launch_bounds__(256) void agg_mm32(const int* __restrict__ off,
                                                const int* __restrict__ ssorted,
                                                const float* __restrict__ Hb,
                                                const float* __restrict__ es,
                                                const float* __restrict__ ed,
                                                const float* __restrict__ bias,  // b3
                                                const float* __restrict__ W4,
                                                const float* __restrict__ as4,
                                                const float* __restrict__ ad4,
                                                float* __restrict__ outp,  // h4
                                                float* __restrict__ es_o,
                                                float* __restrict__ ed_o) {
    __shared__ float lds_ex[8][DEGC];
    __shared__ int lds_s[8][DEGC];
    __shared__ float sW[32][32];
    __shared__ float sV[8][32];
    int tid = threadIdx.x;
    for (int i = tid; i < 1024; i += 256) sW[i >> 5][i & 31] = W4[i];
    __syncthreads();  // sW published
    int wib = tid >> 6, lane = tid & 63;
    int grp = lane >> 5, g = lane & 31;
    int nn = wib * 2 + grp;
    int d = blockIdx.x * 8 + nn;
    int beg = off[d], end = off[d + 1];
    int m = end - beg;

    float edv = ed[d];
    float denp = 0.f;
    for (int base = 0; base < m; base += 32) {
        int e = base + g;
        if (e < m) {
            int s = ssorted[beg + e];
            if (e < DEGC) lds_s[nn][e] = s;
            float a = es[s] + edv;
            a = a > 0.f ? a : 0.2f * a;
            float ex = __expf(a);
            denp += ex;
            if (e < DEGC) lds_ex[nn][e] = ex;
        }
    }
#pragma unroll
    for (int sft = 1; sft < 32; sft <<= 1) denp += __shfl_xor(denp, sft);
    int mu = m < DEGC ? m : DEGC;
    float inv = 1.f / denp;
    for (int idx = g; idx < mu; idx += 32) lds_ex[nn][idx] *= inv;  // premult

    const float4* Hf4 = (const float4*)Hb;
    int sub = g >> 3, q = g & 7;
    float acc[4] = {0.f, 0.f, 0.f, 0.f};
    auto accum = [&](float4 v, float w) {
        acc[0] += w * v.x; acc[1] += w * v.y; acc[2] += w * v.z; acc[3] += w * v.w;
    };
    int i = 0;
    for (; i + 16 <= mu; i += 16) {
        int e0 = i + sub, e1 = e0 + 4, e2 = e0 + 8, e3 = e0 + 12;
        int s0 = lds_s[nn][e0], s1 = lds_s[nn][e1];
        int s2 = lds_s[nn][e2], s3 = lds_s[nn][e3];
        float w0 = lds_ex[nn][e0], w1 = lds_ex[nn][e1];
        float w2 = lds_ex[nn][e2], w3 = lds_ex[nn][e3];
        float4 v0 = Hf4[(size_t)s0 * 8 + q];
        float4 v1 = Hf4[(size_t)s1 * 8 + q];
        float4 v2 = Hf4[(size_t)s2 * 8 + q];
        float4 v3 = Hf4[(size_t)s3 * 8 + q];
        accum(v0, w0); accum(v1, w1); accum(v2, w2); accum(v3, w3);
    }
    for (; i + 8 <= mu; i += 8) {
        int e0 = i + sub, e1 = e0 + 4;
        int s0 = lds_s[nn][e0], s1 = lds_s[nn][e1];
        float w0 = lds_ex[nn][e0], w1 = lds_ex[nn][e1];
        float4 v0 = Hf4[(size_t)s0 * 8 + q];
        float4 v1 = Hf4[(size_t)s1 * 8 + q];
        accum(v0, w0); accum(v1, w1);
    }
    for (; i + 4 <= mu; i += 4) {
        int e = i + sub;
        accum(Hf4[(size_t)lds_s[nn][e] * 8 + q], lds_ex[nn][e]);
    }
    if (i + sub < mu) {
        int e = i + sub;
        accum(Hf4[(size_t)lds_s[nn][e] * 8 + q], lds_ex[nn][e]);
    }
    for (int e = mu + sub; e < m; e += 4) {
        int s = ssorted[beg + e];
        float a = es[s] + edv;
        a = a > 0.f ? a : 0.2f * a;
        accum(Hf4[(size_t)s * 8 + q], __expf(a) * inv);
    }
#pragma unroll
    for (int k = 0; k < 4; ++k) {
        acc[k] += __shfl_xor(acc[k], 8);
        acc[k] += __shfl_xor(acc[k], 16);
    }
    if (sub == 0) {  // 8 lanes publish 32 x4 features to sV
        int c = q * 4;
#pragma unroll
        for (int k = 0; k < 4; ++k) sV[nn][c + k] = fmaxf(acc[k] + bias[c + k], 0.f);
    }
    // same-wave LDS: writes above precede reads below in program order
    float o = 0.f;
#pragma unroll
    for (int f2 = 0; f2 < 32; ++f2) o = fmaf(sV[nn][f2], sW[f2][g], o);
    outp[(size_t)d * 32 + g] = o;
    float ps = o * as4[g], pd = o * ad4[g];
#pragma unroll
    for (int sft = 1; sft < 32; sft <<= 1) { ps += __shfl_xor(ps, sft); pd += __shfl_xor(pd, sft); }
    if (g == 0) { es_o[d] = ps; ed_o[d] = pd; }
}

// ====== fused: GAT5 aggregate (no bias/relu) -> q; out = q @ W5 + b5 ======
// 2 nodes/wave; float4-widened gather; sW staged, barrier right after.
__global__ __launch_bounds__(256) void agg_mm128(const int* __restrict__ off,
                                                 const int* __restrict__ ssorted,
                                                 const float* __restrict__ Hb,
                                                 const float* __restrict__ es,
                                                 const float* __restrict__ ed,
                                                 const float* __restrict__ W5,
                                                 const float* __restrict__ b5,
                                                 float* __restrict__ outp) {
    __shared__ float lds_ex[8][DEGC];
    __shared__ int lds_s[8][DEGC];
    __shared__ float sW[32][128];
    __shared__ float sV[8][32];
    int tid = threadIdx.x;
    for (int i = tid; i < 4096; i += 256) ((float*)sW)[i] = W5[i];
    __syncthreads();  // sW published
    int wib = tid >> 6, lane = tid & 63;
    int grp = lane >> 5, g = lane & 31;
    int nn = wib * 2 + grp;
    int d = blockIdx.x * 8 + nn;
    int beg = off[d], end = off[d + 1];
    int m = end - beg;

    float edv = ed[d];
    float denp = 0.f;
    for (int base = 0; base < m; base += 32) {
        int e = base + g;
        if (e < m) {
            int s = ssorted[beg + e];
            if (e < DEGC) lds_s[nn][e] = s;
            float a = es[s] + edv;
            a = a > 0.f ? a : 0.2f * a;
            float ex = __expf(a);
            denp += ex;
            if (e < DEGC) lds_ex[nn][e] = ex;
        }
    }
#pragma unroll
    for (int sft = 1; sft < 32; sft <<= 1) denp += __shfl_xor(denp, sft);
    int mu = m < DEGC ? m : DEGC;
    float inv = 1.f / denp;
    for (int idx = g; idx < mu; idx += 32) lds_ex[nn][idx] *= inv;  // premult

    const float4* Hf4 = (const float4*)Hb;
    int sub = g >> 3, q = g & 7;
    float acc[4] = {0.f, 0.f, 0.f, 0.f};
    auto accum = [&](float4 v, float w) {
        acc[0] += w * v.x; acc[1] += w * v.y; acc[2] += w * v.z; acc[3] += w * v.w;
    };
    int i = 0;
    for (; i + 16 <= mu; i += 16) {
        int e0 = i + sub, e1 = e0 + 4, e2 = e0 + 8, e3 = e0 + 12;
        int s0 = lds_s[nn][e0], s1 = lds_s[nn][e1];
        int s2 = lds_s[nn][e2], s3 = lds_s[nn][e3];
        float w0 = lds_ex[nn][e0], w1 = lds_ex[nn][e1];
        float w2 = lds_ex[nn][e2], w3 = lds_ex[nn][e3];
        float4 v0 = Hf4[(size_t)s0 * 8 + q];
        float4 v1 = Hf4[(size_t)s1 * 8 + q];
        float4 v2 = Hf4[(size_t)s2 * 8 + q];
        float4 v3 = Hf4[(size_t)s3 * 8 + q];
        accum(v0, w0); accum(v1, w1); accum(v2, w2); accum(v3, w3);
    }
    for (; i + 8 <= mu; i += 8) {
        int e0 = i + sub, e1 = e0 + 4;
        int s0 = lds_s[nn][e0], s1 = lds_s[nn][e1];
        float w0 = lds_ex[nn][e0], w1 = lds_ex[nn][e1];
        float4 v0 = Hf4[(size_t)s0 * 8 + q];
        float4 v1 = Hf4[(size_t)s1 * 8 + q];
        accum(v0, w0); accum(v1, w1);
    }
    for (; i + 4 <= mu; i += 4) {
        int e = i + sub;
        accum(Hf4[(size_t)lds_s[nn][e] * 8 + q], lds_ex[nn][e]);
    }
    if (i + sub < mu) {
        int e = i + sub;
        accum(Hf4[(size_t)lds_s[nn][e] * 8 + q], lds_ex[nn][e]);
    }
    for (int e = mu + sub; e < m; e += 4) {
        int s = ssorted[beg + e];
        float a = es[s] + edv;
        a = a > 0.f ? a : 0.2f * a;
        accum(Hf4[(size_t)s * 8 + q], __expf(a) * inv);
    }
#pragma unroll
    for (int k = 0; k < 4; ++k) {
        acc[k] += __shfl_xor(acc[k], 8);
        acc[k] += __shfl_xor(acc[k], 16);
    }
    if (sub == 0) {  // 8 lanes publish q-vector to sV
        int c = q * 4;
#pragma unroll
        for (int k = 0; k < 4; ++k) sV[nn][c + k] = acc[k];
    }
    // same-wave LDS ordered; epilogue: lane g owns output cols [4g,4g+4)
    float o0 = 0.f, o1 = 0.f, o2 = 0.f, o3 = 0.f;
    int c = g * 4;
#pragma unroll
    for (int f2 = 0; f2 < 32; ++f2) {
        float vv = sV[nn][f2];
        float4 w4 = *(const float4*)&sW[f2][c];
        o0 = fmaf(vv, w4.x, o0);
        o1 = fmaf(vv, w4.y, o1);
        o2 = fmaf(vv, w4.z, o2);
        o3 = fmaf(vv, w4.w, o3);
    }
    float4 rb = *(const float4*)&b5[c];
    *(float4*)(outp + (size_t)d * 128 + c) =
        make_float4(o0 + rb.x, o1 + rb.y, o2 + rb.z, o3 + rb.w);
}

// bn + relu + fused GAT5 attn scores (shadowed stats; one 32-lane group per row)
__global__ __launch_bounds__(256) void bn_relu_attn(const float* __restrict__ y,
                                                    const float* __restrict__ sums,
                                                    const float* __restrict__ g,
                                                    const float* __restrict__ be,
                                                    const float* __restrict__ atl,
                                                    float* __restrict__ o,
                                                    float* __restrict__ es,
                                                    float* __restrict__ ed) {
    __shared__ float ssc[32], ssh[32];
    int t = threadIdx.x;
    if (t < 32) {
        float su = 0.f, sq = 0.f;
#pragma unroll 4
        for (int sh = 0; sh < NSH; ++sh) { su += sums[sh * 64 + t]; sq += sums[sh * 64 + 32 + t]; }
        float mu = su / (float)NNODES;
        float var = sq / (float)NNODES - mu * mu;
        float sc = rsqrtf(var + BN_EPS) * g[t];
        ssc[t] = sc;
        ssh[t] = fmaf(-mu, sc, be[t]);
    }
    __syncthreads();
    int r = blockIdx.x * 8 + (t >> 5);
    int f = t & 31;
    float v = fmaxf(fmaf(y[(size_t)r * 32 + f], ssc[f], ssh[f]), 0.f);
    o[(size_t)r * 32 + f] = v;
    float ps = v * atl[f], pd = v * atl[32 + f];
#pragma unroll
    for (int s = 1; s < 32; s <<= 1) { ps += __shfl_xor(ps, s); pd += __shfl_xor(pd, s); }
    if (f == 0) { es[r] = ps; ed[r] = pd; }
}

extern "C" void kernel_launch(void* const* d_in, const int* in_sizes, int n_in, void* d_out,
                              int out_size, void* d_ws, size_t ws_size, hipStream_t stream) {
    const int N = NNODES, E = NEDGES;
    const float* x = (const float*)d_in[0];
    const int* ei = (const int*)d_in[1];
    const int* src = ei;
    const int* dst = ei + E;
    const float* W1 = (const float*)d_in[2];
    const float* as1 = (const float*)d_in[3];
    const float* ad1 = (const float*)d_in[4];
    const float* b1 = (const float*)d_in[5];
    const float* g1 = (const float*)d_in[6];
    const float* be1 = (const float*)d_in[7];
    const float* W2 = (const float*)d_in[8];
    const float* as2 = (const float*)d_in[9];
    const float* ad2 = (const float*)d_in[10];
    const float* b2 = (const float*)d_in[11];
    const float* g2 = (const float*)d_in[12];
    const float* be2 = (const float*)d_in[13];
    const float* W3 = (const float*)d_in[14];
    const float* as3 = (const float*)d_in[15];
    const float* ad3 = (const float*)d_in[16];
    const float* b3 = (const float*)d_in[17];
    const float* W4 = (const float*)d_in[18];
    const float* as4 = (const float*)d_in[19];
    const float* ad4 = (const float*)d_in[20];
    const float* b4 = (const float*)d_in[21];
    const float* g4 = (const float*)d_in[22];
    const float* be4 = (const float*)d_in[23];
    const float* W5 = (const float*)d_in[24];
    const float* as5 = (const float*)d_in[25];
    const float* ad5 = (const float*)d_in[26];
    const float* b5 = (const float*)d_in[27];
    float* out = (float*)d_out;

    // workspace layout (float-sized slots)
    float* ws = (float*)d_ws;
    float* bufAf = ws;                                      // N*128 fp32
    float* bufB = ws + (size_t)N * 128;                     // N*128 fp32
    ushort* bufAbf = (ushort*)(ws + (size_t)2 * N * 128);   // N*128 bf16
    uint* ebuf = (uint*)bufAf;                              // E uints, aliased to bufAf
    float* esA = ws + (size_t)2 * N * 128 + (size_t)N * 64; // N*4
    float* edA = esA + (size_t)N * 4;                       // N*4
    float* esB = edA + (size_t)N * 4;                       // N*4
    float* edB = esB + (size_t)N * 4;                       // N*4
    float* sums = edB + (size_t)N * 4;                      // NSH*576
    float* sumsA = sums;                                    // NSH*256
    float* sumsB = sums + (size_t)NSH * 256;                // NSH*256
    float* sums32 = sums + (size_t)2 * NSH * 256;           // NSH*64
    int* bcnt = (int*)(sums + (size_t)NSH * 576);           // NB
    int* eoff = bcnt + NB;                                  // NB+1
    int* boff = eoff + NB + 1;                              // NB+1
    int* ecur = boff + NB + 1;                              // NB
    float* atl = (float*)(ecur + NB);                       // 64 (ãs | ãd)
    int* off = (int*)(atl + 64);                            // N+1
    int* ssorted = off + N + 1;                             // E+N
    size_t wtoff = (((size_t)((ssorted + E + N) - (int*)ws)) + 3) & ~(size_t)3;
    ushort* wt1h = (ushort*)((int*)ws + wtoff);             // 128*128
    ushort* wt1l = wt1h + 16384;
    ushort* wt2h = wt1l + 16384;
    ushort* wt2l = wt2h + 16384;
    ushort* wt3h = wt2l + 16384;                            // 32*128
    ushort* wt3l = wt3h + 4096;

    const int TB = 256;
    const int gAgg = N / 4;   // 1-node-per-wave kernels (bf4)
    const int gAgg2 = N / 8;  // 2-node-per-wave kernels (F=32)
    const int gMM = (N + 63) / 64;  // 782 blocks
    const float inv_n = 1.f / (float)N;

    // zero shadowed sums + bcnt in one contiguous shot
    hipMemsetAsync(sums, 0, ((size_t)NSH * 576 + NB) * sizeof(float), stream);

    // ---- CSR build + weight split (hist ∥ wt in one kernel) ----
    histwt<<<HWG + 144, TB, 0, stream>>>(dst, bcnt, W1, W2, W3, wt1h, wt1l, wt2h, wt2l,
                                         wt3h, wt3l);
    bucket_scan<<<1, 512, 0, stream>>>(bcnt, eoff, boff, ecur, off, W5, as5, ad5, atl);

    // ===== scatter ∥ GAT1: 128 -> 4x32 (split-MFMA) in one dispatch =====
    scatter_mm<<<SCG + gMM, TB, 0, stream>>>(src, dst, eoff, ecur, ebuf, x, wt1h, wt1l,
                                             as1, ad1, bufAbf, esA, edA, N);
    bucket_place<<<NB, TB, 0, stream>>>(ebuf, eoff, boff, off, ssorted);

    // ===== GAT1 agg + fused bn1 stats =====
    node_agg_bf4<<<gAgg, TB, 0, stream>>>(off, ssorted, bufAbf, esA, edA, b1, bufB, sumsA);

    // ===== GAT2: 128 -> 4x32 (split-MFMA, bn1 fused); agg + fused bn2 stats =====
    mfma_mm<128, true, true><<<gMM, TB, 0, stream>>>(
        bufB, wt2h, wt2l, sumsA, g1, be1, as2, ad2, nullptr, bufAbf, esB, edB,
        N, inv_n);
    node_agg_bf4<<<gAgg, TB, 0, stream>>>(off, ssorted, bufAbf, esB, edB, b2, bufB, sumsB);

    // ===== GAT3: 128 -> 32 (split-MFMA, bn2 fused, fp32 h3) =====
    mfma_mm<128, false, true><<<gMM, TB, 0, stream>>>(
        bufB, wt3h, wt3l, sumsB, g2, be2, as3, ad3, bufAf, nullptr, esA, edA,
        N, inv_n);

    // ===== fused: agg3 (relu,+b3) -> x4 -> h4 = x4@W4 + es4/ed4 =====
    agg_mm32<<<gAgg2, TB, 0, stream>>>(off, ssorted, bufAf, esA, edA, b3, W4, as4, ad4,
                                       bufB, esB, edB);

    // ===== GAT4 agg (relu,+b4) + fused bn stats =====
    node_agg_f32s<<<gAgg2, TB, 0, stream>>>(off, ssorted, bufB, esB, edB, b4, bufAf, sums32);
    bn_relu_attn<<<N / 8, TB, 0, stream>>>(bufAf, sums32, g4, be4, atl, bufB, esA, edA);

    // ===== fused: agg5 -> q -> out = q@W5 + b5 =====
    agg_mm128<<<gAgg2, TB, 0, stream>>>(off, ssorted, bufB, esA, edA, W5, b5, out);
}

// Round 12
// 396.922 us; speedup vs baseline: 1.0334x; 1.0334x over previous
//
#include <hip/hip_runtime.h>
#include <math.h>

#define NNODES 50000
#define NEDGES 800000
#define BN_EPS 1e-5f
#define DEGC 128   // LDS-cached in-edges per node; fallback path beyond
#define NB 391     // buckets (128 nodes each; last has 80)
#define NPB 128
#define SCG 256    // scatter blocks (chunked)
#define HWG 192    // histogram blocks inside histwt
#define NSH 32     // bn-stats shadow copies (atomic contention spread)

typedef unsigned int uint;
typedef unsigned short ushort;
typedef __attribute__((ext_vector_type(8))) short bf16x8;
typedef __attribute__((ext_vector_type(4))) float f32x4;

// fp32 -> bf16 (RNE)
static __device__ __forceinline__ ushort f2bf(float f) {
    uint u = __float_as_uint(f);
    return (ushort)((u + 0x7fffu + ((u >> 16) & 1u)) >> 16);
}
static __device__ __forceinline__ float bfhi(ushort h) {
    return __uint_as_float((uint)h << 16);
}
// 2 packed bf16 -> 2 fp32 (elem0 = low 16 bits)
static __device__ __forceinline__ float2 bf2f(uint v) {
    float2 r;
    r.x = __uint_as_float(v << 16);
    r.y = __uint_as_float(v & 0xffff0000u);
    return r;
}
// fp32 -> (hi, lo) bf16 split: v ~= hi + lo with |err| ~ 2^-17 |v|
static __device__ __forceinline__ void splitbf(float v, ushort& h, ushort& l) {
    h = f2bf(v);
    l = f2bf(v - bfhi(h));
}

// ============ fused: bucket histogram (blocks 0..HWG-1) + W transpose/split ============
__global__ __launch_bounds__(256) void histwt(const int* __restrict__ dst,
                                              int* __restrict__ bcnt,
                                              const float* __restrict__ W1,
                                              const float* __restrict__ W2,
                                              const float* __restrict__ W3,
                                              ushort* __restrict__ wt1h, ushort* __restrict__ wt1l,
                                              ushort* __restrict__ wt2h, ushort* __restrict__ wt2l,
                                              ushort* __restrict__ wt3h, ushort* __restrict__ wt3l) {
    if (blockIdx.x < HWG) {
        __shared__ int h[NB];
        for (int i = threadIdx.x; i < NB; i += 256) h[i] = 0;
        __syncthreads();
        for (int e = blockIdx.x * 256 + threadIdx.x; e < NEDGES; e += HWG * 256)
            atomicAdd(&h[dst[e] >> 7], 1);
        __syncthreads();
        for (int i = threadIdx.x; i < NB; i += 256)
            if (h[i]) atomicAdd(&bcnt[i], h[i]);
    } else {
        int idx = (blockIdx.x - HWG) * 256 + threadIdx.x;  // 144*256 = 36864
        ushort h, l;
        if (idx < 16384) {  // W1 128x128
            int k = idx >> 7, c = idx & 127;
            splitbf(W1[idx], h, l);
            wt1h[c * 128 + k] = h; wt1l[c * 128 + k] = l;
        } else if (idx < 32768) {  // W2 128x128
            int i = idx - 16384;
            int k = i >> 7, c = i & 127;
            splitbf(W2[i], h, l);
            wt2h[c * 128 + k] = h; wt2l[c * 128 + k] = l;
        } else {  // W3 128x32
            int i = idx - 32768;
            int k = i >> 5, c = i & 31;
            splitbf(W3[i], h, l);
            wt3h[c * 128 + k] = h; wt3l[c * 128 + k] = l;
        }
    }
}

// scan over buckets (+ fused atilde: atl[0..31]=W5@as5, atl[32..63]=W5@ad5)
__global__ void bucket_scan(const int* __restrict__ bcnt, int* __restrict__ eoff,
                            int* __restrict__ boff, int* __restrict__ ecur,
                            int* __restrict__ off, const float* __restrict__ W5,
                            const float* __restrict__ as5, const float* __restrict__ ad5,
                            float* __restrict__ atl) {
    __shared__ int w1[8], w2[8];
    int t = threadIdx.x, lane = t & 63, wv = t >> 6;  // 512 threads, 8 waves
    int v = (t < NB) ? bcnt[t] : 0;
    int nib = 0;
    if (t < NB) nib = (t == NB - 1) ? (NNODES - (NB - 1) * NPB) : NPB;
    int x1 = v, x2 = v + nib;
#pragma unroll
    for (int s = 1; s < 64; s <<= 1) {
        int t1 = __shfl_up(x1, s), t2 = __shfl_up(x2, s);
        if (lane >= s) { x1 += t1; x2 += t2; }
    }
    if (lane == 63) { w1[wv] = x1; w2[wv] = x2; }
    __syncthreads();
    if (wv == 0) {
        int a = (lane < 8) ? w1[lane] : 0, b = (lane < 8) ? w2[lane] : 0;
#pragma unroll
        for (int s = 1; s < 8; s <<= 1) {
            int ta = __shfl_up(a, s), tb = __shfl_up(b, s);
            if (lane >= s) { a += ta; b += tb; }
        }
        if (lane < 8) { w1[lane] = a; w2[lane] = b; }
    }
    __syncthreads();
    int p1 = (wv > 0) ? w1[wv - 1] : 0, p2 = (wv > 0) ? w2[wv - 1] : 0;
    x1 += p1; x2 += p2;
    if (t < NB) { eoff[t] = x1 - v; boff[t] = x2 - (v + nib); ecur[t] = 0; }
    if (t == NB - 1) { eoff[NB] = x1; boff[NB] = x2; off[NNODES] = x2; }
    if (t >= 448) {  // fused atilde
        int idx = t - 448;
        int k = idx & 31;
        const float* a = (idx < 32) ? as5 : ad5;
        float s = 0.f;
        for (int f = 0; f < 128; ++f) s += W5[k * 128 + f] * a[f];
        atl[idx] = s;
    }
}

// ===== fused: block-aggregated scatter (blocks 0..SCG-1) ∥ GAT1 split-MFMA =====
__global__ __launch_bounds__(256) void scatter_mm(const int* __restrict__ src,
                                                  const int* __restrict__ dst,
                                                  const int* __restrict__ eoff,
                                                  int* __restrict__ ecur,
                                                  uint* __restrict__ ebuf,
                                                  const float* __restrict__ X,
                                                  const ushort* __restrict__ Wth,
                                                  const ushort* __restrict__ Wtl,
                                                  const float* __restrict__ av_s,
                                                  const float* __restrict__ av_d,
                                                  ushort* __restrict__ Obf,
                                                  float* __restrict__ es,
                                                  float* __restrict__ ed, int N) {
    __shared__ int lh[NB];
    __shared__ int lcur[NB];
    __shared__ __align__(16) ushort sAh[64 * 136];
    __shared__ __align__(16) ushort sAl[64 * 136];
    int tid = threadIdx.x;
    if (blockIdx.x < SCG) {  // ---- scatter path ----
        const int CH = (NEDGES + SCG - 1) / SCG;
        int c0 = blockIdx.x * CH;
        int c1 = min(c0 + CH, NEDGES);
        for (int i = tid; i < NB; i += 256) { lh[i] = 0; lcur[i] = 0; }
        __syncthreads();
        for (int e = c0 + tid; e < c1; e += 256) atomicAdd(&lh[dst[e] >> 7], 1);
        __syncthreads();
        for (int i = tid; i < NB; i += 256) {
            int c = lh[i];
            lh[i] = c ? (eoff[i] + atomicAdd(&ecur[i], c)) : 0;
        }
        __syncthreads();
        for (int e = c0 + tid; e < c1; e += 256) {
            int d = dst[e];
            int bk = d >> 7;
            int p = lh[bk] + atomicAdd(&lcur[bk], 1);
            ebuf[p] = ((uint)(d & 127) << 16) | (uint)src[e];
        }
        return;
    }
    // ---- GAT1 mfma path (KK=128, WBF, no AFF) ----
    int rowBase = (int)(blockIdx.x - SCG) * 64;
    int lane = tid & 63, wv = tid >> 6;
    int lr = lane & 15, lq = lane >> 4;
#pragma unroll
    for (int j = 0; j < 8; ++j) {
        int idx = tid + j * 256;
        int row = idx >> 5;
        int cq = idx & 31;
        int gr = rowBase + row;
        float4 v = make_float4(0.f, 0.f, 0.f, 0.f);
        if (gr < N) v = *(const float4*)(X + (size_t)gr * 128 + cq * 4);
        ushort h0, h1, h2, h3, l0, l1, l2, l3;
        splitbf(v.x, h0, l0); splitbf(v.y, h1, l1);
        splitbf(v.z, h2, l2); splitbf(v.w, h3, l3);
        uint2 ph, pl;
        ph.x = (uint)h0 | ((uint)h1 << 16);
        ph.y = (uint)h2 | ((uint)h3 << 16);
        pl.x = (uint)l0 | ((uint)l1 << 16);
        pl.y = (uint)l2 | ((uint)l3 << 16);
        *(uint2*)&sAh[row * 136 + cq * 4] = ph;
        *(uint2*)&sAl[row * 136 + cq * 4] = pl;
    }
    __syncthreads();
    const int ncol0 = wv * 32;
    f32x4 acc[4][2];
#pragma unroll
    for (int mi = 0; mi < 4; ++mi)
#pragma unroll
        for (int ni = 0; ni < 2; ++ni) acc[mi][ni] = (f32x4){0.f, 0.f, 0.f, 0.f};
#pragma unroll
    for (int kq = 0; kq < 4; ++kq) {
        int kb = kq * 32 + lq * 8;
        bf16x8 ah[4], al[4], bh[2], bl[2];
#pragma unroll
        for (int mi = 0; mi < 4; ++mi) {
            ah[mi] = *(const bf16x8*)&sAh[(16 * mi + lr) * 136 + kb];
            al[mi] = *(const bf16x8*)&sAl[(16 * mi + lr) * 136 + kb];
        }
#pragma unroll
        for (int ni = 0; ni < 2; ++ni) {
            size_t bo = (size_t)(ncol0 + 16 * ni + lr) * 128 + kb;
            bh[ni] = *(const bf16x8*)(Wth + bo);
            bl[ni] = *(const bf16x8*)(Wtl + bo);
        }
#pragma unroll
        for (int mi = 0; mi < 4; ++mi)
#pragma unroll
            for (int ni = 0; ni < 2; ++ni) {
                acc[mi][ni] = __builtin_amdgcn_mfma_f32_16x16x32_bf16(
                    ah[mi], bh[ni], acc[mi][ni], 0, 0, 0);
                acc[mi][ni] = __builtin_amdgcn_mfma_f32_16x16x32_bf16(
                    al[mi], bh[ni], acc[mi][ni], 0, 0, 0);
                acc[mi][ni] = __builtin_amdgcn_mfma_f32_16x16x32_bf16(
                    ah[mi], bl[ni], acc[mi][ni], 0, 0, 0);
            }
    }
    {
        float as0 = av_s[ncol0 + lr], as1 = av_s[ncol0 + 16 + lr];
        float ad0 = av_d[ncol0 + lr], ad1 = av_d[ncol0 + 16 + lr];
#pragma unroll
        for (int mi = 0; mi < 4; ++mi)
#pragma unroll
            for (int r = 0; r < 4; ++r) {
                float ps = acc[mi][0][r] * as0 + acc[mi][1][r] * as1;
                float pd = acc[mi][0][r] * ad0 + acc[mi][1][r] * ad1;
#pragma unroll
                for (int s = 1; s < 16; s <<= 1) {
                    ps += __shfl_xor(ps, s);
                    pd += __shfl_xor(pd, s);
                }
                if (lr == 0) {
                    int gr = rowBase + 16 * mi + lq * 4 + r;
                    if (gr < N) {
                        es[(size_t)gr * 4 + wv] = ps;
                        ed[(size_t)gr * 4 + wv] = pd;
                    }
                }
            }
    }
    __syncthreads();
#pragma unroll
    for (int mi = 0; mi < 4; ++mi)
#pragma unroll
        for (int ni = 0; ni < 2; ++ni)
#pragma unroll
            for (int r = 0; r < 4; ++r)
                sAh[(16 * mi + lq * 4 + r) * 136 + ncol0 + 16 * ni + lr] =
                    f2bf(acc[mi][ni][r]);
    __syncthreads();
    int row = tid >> 2, c0 = (tid & 3) * 32;
    int gr = rowBase + row;
    if (gr < N) {
        uint4 o0 = *(const uint4*)&sAh[row * 136 + c0];
        uint4 o1 = *(const uint4*)&sAh[row * 136 + c0 + 8];
        uint4 o2 = *(const uint4*)&sAh[row * 136 + c0 + 16];
        uint4 o3 = *(const uint4*)&sAh[row * 136 + c0 + 24];
        uint4* d4 = (uint4*)(Obf + (size_t)gr * 128 + c0);
        d4[0] = o0; d4[1] = o1; d4[2] = o2; d4[3] = o3;
    }
}

__global__ __launch_bounds__(256) void bucket_place(const uint* __restrict__ ebuf,
                                                    const int* __restrict__ eoff,
                                                    const int* __restrict__ boff,
                                                    int* __restrict__ off,
                                                    int* __restrict__ ssorted) {
    __shared__ int cnt[NPB];
    __shared__ int cur[NPB];
    __shared__ int wtot[2];
    int b = blockIdx.x;
    int nib = (b == NB - 1) ? (NNODES - (NB - 1) * NPB) : NPB;
    int t = threadIdx.x;
    for (int i = t; i < NPB; i += 256) { cnt[i] = 0; cur[i] = 0; }
    __syncthreads();
    int e0 = eoff[b], e1 = eoff[b + 1];
    for (int i = e0 + t; i < e1; i += 256) atomicAdd(&cnt[ebuf[i] >> 16], 1);
    __syncthreads();
    int lane = t & 63, wv = t >> 6;
    int deg = (t < nib) ? cnt[t] + 1 : 0;  // +1 self-loop
    int x = deg;
#pragma unroll
    for (int s = 1; s < 64; s <<= 1) {
        int tv = __shfl_up(x, s);
        if (lane >= s) x += tv;
    }
    if (lane == 63 && wv < 2) wtot[wv] = x;
    __syncthreads();
    int excl = x - deg + ((wv == 1) ? wtot[0] : 0);
    if (t < nib) {
        int base = boff[b] + excl;
        off[b * NPB + t] = base;
        cnt[t] = excl;
        ssorted[base + deg - 1] = b * NPB + t;
    }
    __syncthreads();
    int bb = boff[b];
    for (int i = e0 + t; i < e1; i += 256) {
        uint v = ebuf[i];
        int ld = v >> 16;
        int pos = bb + cnt[ld] + atomicAdd(&cur[ld], 1);
        ssorted[pos] = (int)(v & 0xffffu);
    }
}

// ===== split-bf16 MFMA projection: O = (AFF? bn(X) : X) @ W, fused attn scores =====
template <int KK, bool WBF, bool AFF>
__global__ __launch_bounds__(256) void mfma_mm(const float* __restrict__ X,
                                               const ushort* __restrict__ Wth,
                                               const ushort* __restrict__ Wtl,
                                               const float* __restrict__ bnsums,
                                               const float* __restrict__ bng,
                                               const float* __restrict__ bnbe,
                                               const float* __restrict__ av_s,
                                               const float* __restrict__ av_d,
                                               float* __restrict__ Of,
                                               ushort* __restrict__ Obf,
                                               float* __restrict__ es,
                                               float* __restrict__ ed,
                                               int N, float inv_n) {
    constexpr int KQ = KK / 32;
    constexpr int MI = WBF ? 4 : 1;
    __shared__ __align__(16) ushort sAh[64 * 136];
    __shared__ __align__(16) ushort sAl[64 * 136];
    __shared__ float sSc[128], sSh[128];
    int tid = threadIdx.x;
    int rowBase = blockIdx.x * 64;
    int lane = tid & 63, wv = tid >> 6;
    int lr = lane & 15, lq = lane >> 4;

    if constexpr (AFF) {  // consumer-side bn finalization from shadowed sums
        if (tid < KK) {
            float su = 0.f, sq = 0.f;
#pragma unroll 4
            for (int sh = 0; sh < NSH; ++sh) {
                su += bnsums[sh * 256 + tid];
                sq += bnsums[sh * 256 + 128 + tid];
            }
            float mu = su * inv_n;
            float var = sq * inv_n - mu * mu;
            float s = bng[tid] * rsqrtf(var + BN_EPS);
            sSc[tid] = s;
            sSh[tid] = fmaf(-mu, s, bnbe[tid]);
        }
        __syncthreads();
    }

    // ---- A: 64 x KK fp32 -> hi/lo bf16 LDS ----
#pragma unroll
    for (int j = 0; j < 64 * KK / 4 / 256; ++j) {
        int idx = tid + j * 256;
        int row = idx / (KK / 4);
        int cq = idx - row * (KK / 4);
        int gr = rowBase + row;
        float4 v = make_float4(0.f, 0.f, 0.f, 0.f);
        if (gr < N) {
            v = *(const float4*)(X + (size_t)gr * KK + cq * 4);
            if constexpr (AFF) {
                int c = cq * 4;
                v.x = fmaf(v.x, sSc[c], sSh[c]);
                v.y = fmaf(v.y, sSc[c + 1], sSh[c + 1]);
                v.z = fmaf(v.z, sSc[c + 2], sSh[c + 2]);
                v.w = fmaf(v.w, sSc[c + 3], sSh[c + 3]);
            }
        }
        ushort h0, h1, h2, h3, l0, l1, l2, l3;
        splitbf(v.x, h0, l0); splitbf(v.y, h1, l1);
        splitbf(v.z, h2, l2); splitbf(v.w, h3, l3);
        uint2 ph, pl;
        ph.x = (uint)h0 | ((uint)h1 << 16);
        ph.y = (uint)h2 | ((uint)h3 << 16);
        pl.x = (uint)l0 | ((uint)l1 << 16);
        pl.y = (uint)l2 | ((uint)l3 << 16);
        *(uint2*)&sAh[row * 136 + cq * 4] = ph;
        *(uint2*)&sAl[row * 136 + cq * 4] = pl;
    }
    __syncthreads();

    const int mrow0 = WBF ? 0 : wv * 16;
    const int ncol0 = WBF ? wv * 32 : 0;
    f32x4 acc[MI][2];
#pragma unroll
    for (int mi = 0; mi < MI; ++mi)
#pragma unroll
        for (int ni = 0; ni < 2; ++ni) acc[mi][ni] = (f32x4){0.f, 0.f, 0.f, 0.f};

#pragma unroll
    for (int kq = 0; kq < KQ; ++kq) {
        int kb = kq * 32 + lq * 8;
        bf16x8 ah[MI], al[MI], bh[2], bl[2];
#pragma unroll
        for (int mi = 0; mi < MI; ++mi) {
            ah[mi] = *(const bf16x8*)&sAh[(mrow0 + 16 * mi + lr) * 136 + kb];
            al[mi] = *(const bf16x8*)&sAl[(mrow0 + 16 * mi + lr) * 136 + kb];
        }
#pragma unroll
        for (int ni = 0; ni < 2; ++ni) {
            size_t bo = (size_t)(ncol0 + 16 * ni + lr) * KK + kb;
            bh[ni] = *(const bf16x8*)(Wth + bo);
            bl[ni] = *(const bf16x8*)(Wtl + bo);
        }
#pragma unroll
        for (int mi = 0; mi < MI; ++mi)
#pragma unroll
            for (int ni = 0; ni < 2; ++ni) {
                acc[mi][ni] = __builtin_amdgcn_mfma_f32_16x16x32_bf16(
                    ah[mi], bh[ni], acc[mi][ni], 0, 0, 0);
                acc[mi][ni] = __builtin_amdgcn_mfma_f32_16x16x32_bf16(
                    al[mi], bh[ni], acc[mi][ni], 0, 0, 0);
                acc[mi][ni] = __builtin_amdgcn_mfma_f32_16x16x32_bf16(
                    ah[mi], bl[ni], acc[mi][ni], 0, 0, 0);
            }
    }

    // ---- es/ed from fp32 accumulators ----
    {
        float as0 = av_s[ncol0 + lr], as1 = av_s[ncol0 + 16 + lr];
        float ad0 = av_d[ncol0 + lr], ad1 = av_d[ncol0 + 16 + lr];
#pragma unroll
        for (int mi = 0; mi < MI; ++mi)
#pragma unroll
            for (int r = 0; r < 4; ++r) {
                float ps = acc[mi][0][r] * as0 + acc[mi][1][r] * as1;
                float pd = acc[mi][0][r] * ad0 + acc[mi][1][r] * ad1;
#pragma unroll
                for (int s = 1; s < 16; s <<= 1) {
                    ps += __shfl_xor(ps, s);
                    pd += __shfl_xor(pd, s);
                }
                if (lr == 0) {
                    int gr = rowBase + mrow0 + 16 * mi + lq * 4 + r;
                    if (gr < N) {
                        if constexpr (WBF) {
                            es[(size_t)gr * 4 + wv] = ps;
                            ed[(size_t)gr * 4 + wv] = pd;
                        } else {
                            es[gr] = ps;
                            ed[gr] = pd;
                        }
                    }
                }
            }
    }
    __syncthreads();  // fragment reads done; sAh reusable

    if constexpr (WBF) {
#pragma unroll
        for (int mi = 0; mi < MI; ++mi)
#pragma unroll
            for (int ni = 0; ni < 2; ++ni)
#pragma unroll
                for (int r = 0; r < 4; ++r)
                    sAh[(16 * mi + lq * 4 + r) * 136 + ncol0 + 16 * ni + lr] =
                        f2bf(acc[mi][ni][r]);
        __syncthreads();
        int row = tid >> 2, c0 = (tid & 3) * 32;
        int gr = rowBase + row;
        if (gr < N) {
            uint4 o0 = *(const uint4*)&sAh[row * 136 + c0];
            uint4 o1 = *(const uint4*)&sAh[row * 136 + c0 + 8];
            uint4 o2 = *(const uint4*)&sAh[row * 136 + c0 + 16];
            uint4 o3 = *(const uint4*)&sAh[row * 136 + c0 + 24];
            uint4* d4 = (uint4*)(Obf + (size_t)gr * 128 + c0);
            d4[0] = o0; d4[1] = o1; d4[2] = o2; d4[3] = o3;
        }
    } else {
        float* sOutF = (float*)sAh;  // [64][36] fp32
#pragma unroll
        for (int ni = 0; ni < 2; ++ni)
#pragma unroll
            for (int r = 0; r < 4; ++r)
                sOutF[(mrow0 + lq * 4 + r) * 36 + 16 * ni + lr] = acc[0][ni][r];
        __syncthreads();
        int row = tid >> 2, c0 = (tid & 3) * 8;
        int gr = rowBase + row;
        if (gr < N) {
            float4 v0 = *(const float4*)&sOutF[row * 36 + c0];
            float4 v1 = *(const float4*)&sOutF[row * 36 + c0 + 4];
            *(float4*)(Of + (size_t)gr * 32 + c0) = v0;
            *(float4*)(Of + (size_t)gr * 32 + c0 + 4) = v1;
        }
    }
}

// ====== gather softmax-aggregate, F=128, 4 heads, h in bf16, fused bn-stats ======
// Phase 1: wave-parallel scores; phase 2: uint4 row gather, 8-edge main loop
// (R10 form — 2 outstanding uint4/lane; 16-deep cost occupancy, R11 lesson).
__global__ __launch_bounds__(256) void node_agg_bf4(const int* __restrict__ off,
                                                    const int* __restrict__ ssorted,
                                                    const ushort* __restrict__ Hb,
                                                    const float* __restrict__ es,
                                                    const float* __restrict__ ed,
                                                    const float* __restrict__ bias,
                                                    float* __restrict__ outp,
                                                    float* __restrict__ sums) {
    __shared__ float lds_ex[4][DEGC * 4];
    __shared__ int lds_s[4][DEGC];
    __shared__ float red_v[4][128];
    __shared__ float red_q[4][128];
    int wib = threadIdx.x >> 6;
    int lane = threadIdx.x & 63;
    int d = blockIdx.x * 4 + wib;
    int beg = off[d], end = off[d + 1];
    int m = end - beg;  // >= 1

    // ---- phase 1: scores (wave-parallel over edges x heads) ----
    int lh = lane & 3, le = lane >> 2;
    float edl = ed[(size_t)d * 4 + lh];
    float denp = 0.f;
    for (int base = 0; base < m; base += 16) {
        int e = base + le;
        if (e < m) {
            int s = ssorted[beg + e];
            if (lh == 0 && e < DEGC) lds_s[wib][e] = s;
            float a = es[(size_t)s * 4 + lh] + edl;
            a = a > 0.f ? a : 0.2f * a;
            float ex = __expf(a);
            denp += ex;
            if (e < DEGC) lds_ex[wib][e * 4 + lh] = ex;
        }
    }
#pragma unroll
    for (int sft = 4; sft < 64; sft <<= 1) denp += __shfl_xor(denp, sft);
    float inv = 1.f / denp;  // per-lane: inverse denom of head lh
    int mu = m < DEGC ? m : DEGC;
    // premultiply (idx & 3 == lh for stride-64 walk -> lane's own inv applies)
    for (int idx = lane; idx < mu * 4; idx += 64) lds_ex[wib][idx] *= inv;

    // ---- phase 2: uint4 weighted row gather ----
    const uint4* Hu4 = (const uint4*)Hb;  // 16 uint4 per 128-bf16 row
    int sub = lane >> 4, fl = lane & 15;  // edge subset, feature quad [8fl,8fl+8)
    int head = fl >> 2;
    float inv2 = __shfl(inv, head);  // fallback path only
    float edl2 = __shfl(edl, head);
    float acc[8];
#pragma unroll
    for (int k = 0; k < 8; ++k) acc[k] = 0.f;

    auto accum = [&](uint4 v, float w) {
        float2 f;
        f = bf2f(v.x); acc[0] += w * f.x; acc[1] += w * f.y;
        f = bf2f(v.y); acc[2] += w * f.x; acc[3] += w * f.y;
        f = bf2f(v.z); acc[4] += w * f.x; acc[5] += w * f.y;
        f = bf2f(v.w); acc[6] += w * f.x; acc[7] += w * f.y;
    };

    int i = 0;
    for (; i + 8 <= mu; i += 8) {  // 2 edges per lane per iter
        int e0 = i + sub, e1 = e0 + 4;
        int s0 = lds_s[wib][e0], s1 = lds_s[wib][e1];
        float w0 = lds_ex[wib][e0 * 4 + head];
        float w1 = lds_ex[wib][e1 * 4 + head];
        uint4 v0 = Hu4[(size_t)s0 * 16 + fl];
        uint4 v1 = Hu4[(size_t)s1 * 16 + fl];
        accum(v0, w0);
        accum(v1, w1);
    }
    for (; i + 4 <= mu; i += 4) {
        int e = i + sub;
        int s = lds_s[wib][e];
        float w = lds_ex[wib][e * 4 + head];
        uint4 v = Hu4[(size_t)s * 16 + fl];
        accum(v, w);
    }
    if (i + sub < mu) {  // tail (<4 edges)
        int e = i + sub;
        int s = lds_s[wib][e];
        float w = lds_ex[wib][e * 4 + head];
        uint4 v = Hu4[(size_t)s * 16 + fl];
        accum(v, w);
    }
    for (int e = mu + sub; e < m; e += 4) {  // rare high-degree fallback
        int s = ssorted[beg + e];
        float a = es[(size_t)s * 4 + head] + edl2;
        a = a > 0.f ? a : 0.2f * a;
        float w = __expf(a) * inv2;
        uint4 v = Hu4[(size_t)s * 16 + fl];
        accum(v, w);
    }
    // combine the 4 edge subsets (xor 16: sub0<->1, 2<->3; xor 32: pairs)
#pragma unroll
    for (int k = 0; k < 8; ++k) {
        acc[k] += __shfl_xor(acc[k], 16);
        acc[k] += __shfl_xor(acc[k], 32);
    }
    if (sub == 0) {  // 16 lanes cover the 128-feature row, 32B each
        int c = fl * 8;
        float v[8];
#pragma unroll
        for (int k = 0; k < 8; ++k) v[k] = fmaxf(acc[k] + bias[c + k], 0.f);
        *(float4*)(outp + (size_t)d * 128 + c) = make_float4(v[0], v[1], v[2], v[3]);
        *(float4*)(outp + (size_t)d * 128 + c + 4) = make_float4(v[4], v[5], v[6], v[7]);
#pragma unroll
        for (int k = 0; k < 8; ++k) {
            red_v[wib][c + k] = v[k];
            red_q[wib][c + k] = v[k] * v[k];
        }
    }
    __syncthreads();
    // ---- fused bn stats: per-block reduce -> shadowed atomics ----
    int t = threadIdx.x;
    int sh = (blockIdx.x & (NSH - 1)) * 256;
    if (t < 128) {
        float s = red_v[0][t] + red_v[1][t] + red_v[2][t] + red_v[3][t];
        atomicAdd(&sums[sh + t], s);
    } else {
        int u = t - 128;
        float q = red_q[0][u] + red_q[1][u] + red_q[2][u] + red_q[3][u];
        atomicAdd(&sums[sh + 128 + u], q);
    }
}

// ====== gather softmax-aggregate F=32 fp32, fused bn-stats (GAT4 agg) ======
// 2 nodes/wave; float4-widened phase 2 (R11 win): lane = (sub=g>>3, quad q=g&7),
// 16-edge main loop. Subset partials combined via xor 8,16 (group-local).
__global__ __launch_bounds__(256) void node_agg_f32s(const int* __restrict__ off,
                                                     const int* __restrict__ ssorted,
                                                     const float* __restrict__ Hb,
                                                     const float* __restrict__ es,
                                                     const float* __restrict__ ed,
                                                     const float* __restrict__ bias,
                                                     float* __restrict__ outp,
                                                     float* __restrict__ sums) {
    __shared__ float lds_ex[8][DEGC];
    __shared__ int lds_s[8][DEGC];
    __shared__ float red_v[8][32];
    __shared__ float red_q[8][32];
    int tid = threadIdx.x;
    int wib = tid >> 6, lane = tid & 63;
    int grp = lane >> 5, g = lane & 31;
    int nn = wib * 2 + grp;
    int d = blockIdx.x * 8 + nn;
    int beg = off[d], end = off[d + 1];
    int m = end - beg;

    float edv = ed[d];
    float denp = 0.f;
    for (int base = 0; base < m; base += 32) {
        int e = base + g;
        if (e < m) {
            int s = ssorted[beg + e];
            if (e < DEGC) lds_s[nn][e] = s;
            float a = es[s] + edv;
            a = a > 0.f ? a : 0.2f * a;
            float ex = __expf(a);
            denp += ex;
            if (e < DEGC) lds_ex[nn][e] = ex;
        }
    }
#pragma unroll
    for (int sft = 1; sft < 32; sft <<= 1) denp += __shfl_xor(denp, sft);
    int mu = m < DEGC ? m : DEGC;
    float inv = 1.f / denp;
    for (int idx = g; idx < mu; idx += 32) lds_ex[nn][idx] *= inv;  // premult

    const float4* Hf4 = (const float4*)Hb;  // 8 float4 per 32-f row
    int sub = g >> 3, q = g & 7;            // edge subset, feature quad [4q,4q+4)
    float acc[4] = {0.f, 0.f, 0.f, 0.f};
    auto accum = [&](float4 v, float w) {
        acc[0] += w * v.x; acc[1] += w * v.y; acc[2] += w * v.z; acc[3] += w * v.w;
    };
    int i = 0;
    for (; i + 16 <= mu; i += 16) {  // 4 edges/lane
        int e0 = i + sub, e1 = e0 + 4, e2 = e0 + 8, e3 = e0 + 12;
        int s0 = lds_s[nn][e0], s1 = lds_s[nn][e1];
        int s2 = lds_s[nn][e2], s3 = lds_s[nn][e3];
        float w0 = lds_ex[nn][e0], w1 = lds_ex[nn][e1];
        float w2 = lds_ex[nn][e2], w3 = lds_ex[nn][e3];
        float4 v0 = Hf4[(size_t)s0 * 8 + q];
        float4 v1 = Hf4[(size_t)s1 * 8 + q];
        float4 v2 = Hf4[(size_t)s2 * 8 + q];
        float4 v3 = Hf4[(size_t)s3 * 8 + q];
        accum(v0, w0); accum(v1, w1); accum(v2, w2); accum(v3, w3);
    }
    for (; i + 8 <= mu; i += 8) {
        int e0 = i + sub, e1 = e0 + 4;
        int s0 = lds_s[nn][e0], s1 = lds_s[nn][e1];
        float w0 = lds_ex[nn][e0], w1 = lds_ex[nn][e1];
        float4 v0 = Hf4[(size_t)s0 * 8 + q];
        float4 v1 = Hf4[(size_t)s1 * 8 + q];
        accum(v0, w0); accum(v1, w1);
    }
    for (; i + 4 <= mu; i += 4) {
        int e = i + sub;
        accum(Hf4[(size_t)lds_s[nn][e] * 8 + q], lds_ex[nn][e]);
    }
    if (i + sub < mu) {
        int e = i + sub;
        accum(Hf4[(size_t)lds_s[nn][e] * 8 + q], lds_ex[nn][e]);
    }
    for (int e = mu + sub; e < m; e += 4) {  // rare high-degree fallback
        int s = ssorted[beg + e];
        float a = es[s] + edv;
        a = a > 0.f ? a : 0.2f * a;
        accum(Hf4[(size_t)s * 8 + q], __expf(a) * inv);
    }
#pragma unroll
    for (int k = 0; k < 4; ++k) {
        acc[k] += __shfl_xor(acc[k], 8);
        acc[k] += __shfl_xor(acc[k], 16);
    }
    if (sub == 0) {  // 8 lanes cover 32 features
        int c = q * 4;
        float v[4];
#pragma unroll
        for (int k = 0; k < 4; ++k) v[k] = fmaxf(acc[k] + bias[c + k], 0.f);
        *(float4*)(outp + (size_t)d * 32 + c) = make_float4(v[0], v[1], v[2], v[3]);
#pragma unroll
        for (int k = 0; k < 4; ++k) {
            red_v[nn][c + k] = v[k];
            red_q[nn][c + k] = v[k] * v[k];
        }
    }
    __syncthreads();
    int sh = (blockIdx.x & (NSH - 1)) * 64;
    if (tid < 32) {
        float s = 0.f;
#pragma unroll
        for (int k = 0; k < 8; ++k) s += red_v[k][tid];
        atomicAdd(&sums[sh + tid], s);
    } else if (tid < 64) {
        int u = tid - 32;
        float q2 = 0.f;
#pragma unroll
        for (int k = 0; k < 8; ++k) q2 += red_q[k][u];
        atomicAdd(&sums[sh + 32 + u], q2);
    }
}

// ====== fused: GAT3 aggregate (relu, +b3) -> x4; h4 = x4 @ W4; es4/ed4 ======
// 2 nodes/wave; float4-widened gather; sW staged, barrier right after.
__global__ __launch_bounds__(256) void agg_mm32(const int* __restrict__ off,
                                                const int* __restrict__ ssorted,
                                                const float* __restrict__ Hb,
                                                const float* __restrict__ es,
                                                const float* __restrict__ ed,
                                                const float* __restrict__ bias,  // b3
                                                const float* __restrict__ W4,
                                                const float* __restrict__ as4,
                                                const float* __restrict__ ad4,
                                                float* __restrict__ outp,  // h4
                                                float* __restrict__ es_o,
                                                float* __restrict__ ed_o) {
    __shared__ float lds_ex[8][DEGC];
    __shared__ int lds_s[8][DEGC];
    __shared__ float sW[32][32];
    __shared__ float sV[8][32];
    int tid = threadIdx.x;
    for (int i = tid; i < 1024; i += 256) sW[i >> 5][i & 31] = W4[i];
    __syncthreads();  // sW published
    int wib = tid >> 6, lane = tid & 63;
    int grp = lane >> 5, g = lane & 31;
    int nn = wib * 2 + grp;
    int d = blockIdx.x * 8 + nn;
    int beg = off[d], end = off[d + 1];
    int m = end - beg;

    float edv = ed[d];
    float denp = 0.f;
    for (int base = 0; base < m; base += 32) {
        int e = base + g;
        if (e < m) {
            int s = ssorted[beg + e];
            if (e < DEGC) lds_s[nn][e] = s;
            float a = es[s] + edv;
            a = a > 0.f ? a : 0.2f * a;
            float ex = __expf(a);
            denp += ex;
            if (e < DEGC) lds_ex[nn][e] = ex;
        }
    }
#pragma unroll
    for (int sft = 1; sft < 32; sft <<= 1) denp += __shfl_xor(denp, sft);
    int mu = m < DEGC ? m : DEGC;
    float inv = 1.f / denp;
    for (int idx = g; idx < mu; idx += 32) lds_ex[nn][idx] *= inv;  // premult

    const float4* Hf4 = (const float4*)Hb;
    int sub = g >> 3, q = g & 7;
    float acc[4] = {0.f, 0.f, 0.f, 0.f};
    auto accum = [&](float4 v, float w) {
        acc[0] += w * v.x; acc[1] += w * v.y; acc[2] += w * v.z; acc[3] += w * v.w;
    };
    int i = 0;
    for (; i + 16 <= mu; i += 16) {
        int e0 = i + sub, e1 = e0 + 4, e2 = e0 + 8, e3 = e0 + 12;
        int s0 = lds_s[nn][e0], s1 = lds_s[nn][e1];
        int s2 = lds_s[nn][e2], s3 = lds_s[nn][e3];
        float w0 = lds_ex[nn][e0], w1 = lds_ex[nn][e1];
        float w2 = lds_ex[nn][e2], w3 = lds_ex[nn][e3];
        float4 v0 = Hf4[(size_t)s0 * 8 + q];
        float4 v1 = Hf4[(size_t)s1 * 8 + q];
        float4 v2 = Hf4[(size_t)s2 * 8 + q];
        float4 v3 = Hf4[(size_t)s3 * 8 + q];
        accum(v0, w0); accum(v1, w1); accum(v2, w2); accum(v3, w3);
    }
    for (; i + 8 <= mu; i += 8) {
        int e0 = i + sub, e1 = e0 + 4;
        int s0 = lds_s[nn][e0], s1 = lds_s[nn][e1];
        float w0 = lds_ex[nn][e0], w1 = lds_ex[nn][e1];
        float4 v0 = Hf4[(size_t)s0 * 8 + q];
        float4 v1 = Hf4[(size_t)s1 * 8 + q];
        accum(v0, w0); accum(v1, w1);
    }
    for (; i + 4 <= mu; i += 4) {
        int e = i + sub;
        accum(Hf4[(size_t)lds_s[nn][e] * 8 + q], lds_ex[nn][e]);
    }
    if (i + sub < mu) {
        int e = i + sub;
        accum(Hf4[(size_t)lds_s[nn][e] * 8 + q], lds_ex[nn][e]);
    }
    for (int e = mu + sub; e < m; e += 4) {
        int s = ssorted[beg + e];
        float a = es[s] + edv;
        a = a > 0.f ? a : 0.2f * a;
        accum(Hf4[(size_t)s * 8 + q], __expf(a) * inv);
    }
#pragma unroll
    for (int k = 0; k < 4; ++k) {
        acc[k] += __shfl_xor(acc[k], 8);
        acc[k] += __shfl_xor(acc[k], 16);
    }
    if (sub == 0) {  // 8 lanes publish 32 x4 features to sV
        int c = q * 4;
#pragma unroll
        for (int k = 0; k < 4; ++k) sV[nn][c + k] = fmaxf(acc[k] + bias[c + k], 0.f);
    }
    // same-wave LDS: writes above precede reads below in program order
    float o = 0.f;
#pragma unroll
    for (int f2 = 0; f2 < 32; ++f2) o = fmaf(sV[nn][f2], sW[f2][g], o);
    outp[(size_t)d * 32 + g] = o;
    float ps = o * as4[g], pd = o * ad4[g];
#pragma unroll
    for (int sft = 1; sft < 32; sft <<= 1) { ps += __shfl_xor(ps, sft); pd += __shfl_xor(pd, sft); }
    if (g == 0) { es_o[d] = ps; ed_o[d] = pd; }
}

// ====== fused: GAT5 aggregate (no bias/relu) -> q; out = q @ W5 + b5 ======
// 2 nodes/wave; float4-widened gather; sW staged, barrier right after.
__global__ __launch_bounds__(256) void agg_mm128(const int* __restrict__ off,
                                                 const int* __restrict__ ssorted,
                                                 const float* __restrict__ Hb,
                                                 const float* __restrict__ es,
                                                 const float* __restrict__ ed,
                                                 const float* __restrict__ W5,
                                                 const float* __restrict__ b5,
                                                 float* __restrict__ outp) {
    __shared__ float lds_ex[8][DEGC];
    __shared__ int lds_s[8][DEGC];
    __shared__ float sW[32][128];
    __shared__ float sV[8][32];
    int tid = threadIdx.x;
    for (int i = tid; i < 4096; i += 256) ((float*)sW)[i] = W5[i];
    __syncthreads();  // sW published
    int wib = tid >> 6, lane = tid & 63;
    int grp = lane >> 5, g = lane & 31;
    int nn = wib * 2 + grp;
    int d = blockIdx.x * 8 + nn;
    int beg = off[d], end = off[d + 1];
    int m = end - beg;

    float edv = ed[d];
    float denp = 0.f;
    for (int base = 0; base < m; base += 32) {
        int e = base + g;
        if (e < m) {
            int s = ssorted[beg + e];
            if (e < DEGC) lds_s[nn][e] = s;
            float a = es[s] + edv;
            a = a > 0.f ? a : 0.2f * a;
            float ex = __expf(a);
            denp += ex;
            if (e < DEGC) lds_ex[nn][e] = ex;
        }
    }
#pragma unroll
    for (int sft = 1; sft < 32; sft <<= 1) denp += __shfl_xor(denp, sft);
    int mu = m < DEGC ? m : DEGC;
    float inv = 1.f / denp;
    for (int idx = g; idx < mu; idx += 32) lds_ex[nn][idx] *= inv;  // premult

    const float4* Hf4 = (const float4*)Hb;
    int sub = g >> 3, q = g & 7;
    float acc[4] = {0.f, 0.f, 0.f, 0.f};
    auto accum = [&](float4 v, float w) {
        acc[0] += w * v.x; acc[1] += w * v.y; acc[2] += w * v.z; acc[3] += w * v.w;
    };
    int i = 0;
    for (; i + 16 <= mu; i += 16) {
        int e0 = i + sub, e1 = e0 + 4, e2 = e0 + 8, e3 = e0 + 12;
        int s0 = lds_s[nn][e0], s1 = lds_s[nn][e1];
        int s2 = lds_s[nn][e2], s3 = lds_s[nn][e3];
        float w0 = lds_ex[nn][e0], w1 = lds_ex[nn][e1];
        float w2 = lds_ex[nn][e2], w3 = lds_ex[nn][e3];
        float4 v0 = Hf4[(size_t)s0 * 8 + q];
        float4 v1 = Hf4[(size_t)s1 * 8 + q];
        float4 v2 = Hf4[(size_t)s2 * 8 + q];
        float4 v3 = Hf4[(size_t)s3 * 8 + q];
        accum(v0, w0); accum(v1, w1); accum(v2, w2); accum(v3, w3);
    }
    for (; i + 8 <= mu; i += 8) {
        int e0 = i + sub, e1 = e0 + 4;
        int s0 = lds_s[nn][e0], s1 = lds_s[nn][e1];
        float w0 = lds_ex[nn][e0], w1 = lds_ex[nn][e1];
        float4 v0 = Hf4[(size_t)s0 * 8 + q];
        float4 v1 = Hf4[(size_t)s1 * 8 + q];
        accum(v0, w0); accum(v1, w1);
    }
    for (; i + 4 <= mu; i += 4) {
        int e = i + sub;
        accum(Hf4[(size_t)lds_s[nn][e] * 8 + q], lds_ex[nn][e]);
    }
    if (i + sub < mu) {
        int e = i + sub;
        accum(Hf4[(size_t)lds_s[nn][e] * 8 + q], lds_ex[nn][e]);
    }
    for (int e = mu + sub; e < m; e += 4) {
        int s = ssorted[beg + e];
        float a = es[s] + edv;
        a = a > 0.f ? a : 0.2f * a;
        accum(Hf4[(size_t)s * 8 + q], __expf(a) * inv);
    }
#pragma unroll
    for (int k = 0; k < 4; ++k) {
        acc[k] += __shfl_xor(acc[k], 8);
        acc[k] += __shfl_xor(acc[k], 16);
    }
    if (sub == 0) {  // 8 lanes publish q-vector to sV
        int c = q * 4;
#pragma unroll
        for (int k = 0; k < 4; ++k) sV[nn][c + k] = acc[k];
    }
    // same-wave LDS ordered; epilogue: lane g owns output cols [4g,4g+4)
    float o0 = 0.f, o1 = 0.f, o2 = 0.f, o3 = 0.f;
    int c = g * 4;
#pragma unroll
    for (int f2 = 0; f2 < 32; ++f2) {
        float vv = sV[nn][f2];
        float4 w4 = *(const float4*)&sW[f2][c];
        o0 = fmaf(vv, w4.x, o0);
        o1 = fmaf(vv, w4.y, o1);
        o2 = fmaf(vv, w4.z, o2);
        o3 = fmaf(vv, w4.w, o3);
    }
    float4 rb = *(const float4*)&b5[c];
    *(float4*)(outp + (size_t)d * 128 + c) =
        make_float4(o0 + rb.x, o1 + rb.y, o2 + rb.z, o3 + rb.w);
}

// bn + relu + fused GAT5 attn scores (shadowed stats; one 32-lane group per row)
__global__ __launch_bounds__(256) void bn_relu_attn(const float* __restrict__ y,
                                                    const float* __restrict__ sums,
                                                    const float* __restrict__ g,
                                                    const float* __restrict__ be,
                                                    const float* __restrict__ atl,
                                                    float* __restrict__ o,
                                                    float* __restrict__ es,
                                                    float* __restrict__ ed) {
    __shared__ float ssc[32], ssh[32];
    int t = threadIdx.x;
    if (t < 32) {
        float su = 0.f, sq = 0.f;
#pragma unroll 4
        for (int sh = 0; sh < NSH; ++sh) { su += sums[sh * 64 + t]; sq += sums[sh * 64 + 32 + t]; }
        float mu = su / (float)NNODES;
        float var = sq / (float)NNODES - mu * mu;
        float sc = rsqrtf(var + BN_EPS) * g[t];
        ssc[t] = sc;
        ssh[t] = fmaf(-mu, sc, be[t]);
    }
    __syncthreads();
    int r = blockIdx.x * 8 + (t >> 5);
    int f = t & 31;
    float v = fmaxf(fmaf(y[(size_t)r * 32 + f], ssc[f], ssh[f]), 0.f);
    o[(size_t)r * 32 + f] = v;
    float ps = v * atl[f], pd = v * atl[32 + f];
#pragma unroll
    for (int s = 1; s < 32; s <<= 1) { ps += __shfl_xor(ps, s); pd += __shfl_xor(pd, s); }
    if (f == 0) { es[r] = ps; ed[r] = pd; }
}

extern "C" void kernel_launch(void* const* d_in, const int* in_sizes, int n_in, void* d_out,
                              int out_size, void* d_ws, size_t ws_size, hipStream_t stream) {
    const int N = NNODES, E = NEDGES;
    const float* x = (const float*)d_in[0];
    const int* ei = (const int*)d_in[1];
    const int* src = ei;
    const int* dst = ei + E;
    const float* W1 = (const float*)d_in[2];
    const float* as1 = (const float*)d_in[3];
    const float* ad1 = (const float*)d_in[4];
    const float* b1 = (const float*)d_in[5];
    const float* g1 = (const float*)d_in[6];
    const float* be1 = (const float*)d_in[7];
    const float* W2 = (const float*)d_in[8];
    const float* as2 = (const float*)d_in[9];
    const float* ad2 = (const float*)d_in[10];
    const float* b2 = (const float*)d_in[11];
    const float* g2 = (const float*)d_in[12];
    const float* be2 = (const float*)d_in[13];
    const float* W3 = (const float*)d_in[14];
    const float* as3 = (const float*)d_in[15];
    const float* ad3 = (const float*)d_in[16];
    const float* b3 = (const float*)d_in[17];
    const float* W4 = (const float*)d_in[18];
    const float* as4 = (const float*)d_in[19];
    const float* ad4 = (const float*)d_in[20];
    const float* b4 = (const float*)d_in[21];
    const float* g4 = (const float*)d_in[22];
    const float* be4 = (const float*)d_in[23];
    const float* W5 = (const float*)d_in[24];
    const float* as5 = (const float*)d_in[25];
    const float* ad5 = (const float*)d_in[26];
    const float* b5 = (const float*)d_in[27];
    float* out = (float*)d_out;

    // workspace layout (float-sized slots)
    float* ws = (float*)d_ws;
    float* bufAf = ws;                                      // N*128 fp32
    float* bufB = ws + (size_t)N * 128;                     // N*128 fp32
    ushort* bufAbf = (ushort*)(ws + (size_t)2 * N * 128);   // N*128 bf16
    uint* ebuf = (uint*)bufAf;                              // E uints, aliased to bufAf
    float* esA = ws + (size_t)2 * N * 128 + (size_t)N * 64; // N*4
    float* edA = esA + (size_t)N * 4;                       // N*4
    float* esB = edA + (size_t)N * 4;                       // N*4
    float* edB = esB + (size_t)N * 4;                       // N*4
    float* sums = edB + (size_t)N * 4;                      // NSH*576
    float* sumsA = sums;                                    // NSH*256
    float* sumsB = sums + (size_t)NSH * 256;                // NSH*256
    float* sums32 = sums + (size_t)2 * NSH * 256;           // NSH*64
    int* bcnt = (int*)(sums + (size_t)NSH * 576);           // NB
    int* eoff = bcnt + NB;                                  // NB+1
    int* boff = eoff + NB + 1;                              // NB+1
    int* ecur = boff + NB + 1;                              // NB
    float* atl = (float*)(ecur + NB);                       // 64 (ãs | ãd)
    int* off = (int*)(atl + 64);                            // N+1
    int* ssorted = off + N + 1;                             // E+N
    size_t wtoff = (((size_t)((ssorted + E + N) - (int*)ws)) + 3) & ~(size_t)3;
    ushort* wt1h = (ushort*)((int*)ws + wtoff);             // 128*128
    ushort* wt1l = wt1h + 16384;
    ushort* wt2h = wt1l + 16384;
    ushort* wt2l = wt2h + 16384;
    ushort* wt3h = wt2l + 16384;                            // 32*128
    ushort* wt3l = wt3h + 4096;

    const int TB = 256;
    const int gAgg = N / 4;   // 1-node-per-wave kernels (bf4)
    const int gAgg2 = N / 8;  // 2-node-per-wave kernels (F=32)
    const int gMM = (N + 63) / 64;  // 782 blocks
    const float inv_n = 1.f / (float)N;

    // zero shadowed sums + bcnt in one contiguous shot
    hipMemsetAsync(sums, 0, ((size_t)NSH * 576 + NB) * sizeof(float), stream);

    // ---- CSR build + weight split (hist ∥ wt in one kernel) ----
    histwt<<<HWG + 144, TB, 0, stream>>>(dst, bcnt, W1, W2, W3, wt1h, wt1l, wt2h, wt2l,
                                         wt3h, wt3l);
    bucket_scan<<<1, 512, 0, stream>>>(bcnt, eoff, boff, ecur, off, W5, as5, ad5, atl);

    // ===== scatter ∥ GAT1: 128 -> 4x32 (split-MFMA) in one dispatch =====
    scatter_mm<<<SCG + gMM, TB, 0, stream>>>(src, dst, eoff, ecur, ebuf, x, wt1h, wt1l,
                                             as1, ad1, bufAbf, esA, edA, N);
    bucket_place<<<NB, TB, 0, stream>>>(ebuf, eoff, boff, off, ssorted);

    // ===== GAT1 agg + fused bn1 stats =====
    node_agg_bf4<<<gAgg, TB, 0, stream>>>(off, ssorted, bufAbf, esA, edA, b1, bufB, sumsA);

    // ===== GAT2: 128 -> 4x32 (split-MFMA, bn1 fused); agg + fused bn2 stats =====
    mfma_mm<128, true, true><<<gMM, TB, 0, stream>>>(
        bufB, wt2h, wt2l, sumsA, g1, be1, as2, ad2, nullptr, bufAbf, esB, edB,
        N, inv_n);
    node_agg_bf4<<<gAgg, TB, 0, stream>>>(off, ssorted, bufAbf, esB, edB, b2, bufB, sumsB);

    // ===== GAT3: 128 -> 32 (split-MFMA, bn2 fused, fp32 h3) =====
    mfma_mm<128, false, true><<<gMM, TB, 0, stream>>>(
        bufB, wt3h, wt3l, sumsB, g2, be2, as3, ad3, bufAf, nullptr, esA, edA,
        N, inv_n);

    // ===== fused: agg3 (relu,+b3) -> x4 -> h4 = x4@W4 + es4/ed4 =====
    agg_mm32<<<gAgg2, TB, 0, stream>>>(off, ssorted, bufAf, esA, edA, b3, W4, as4, ad4,
                                       bufB, esB, edB);

    // ===== GAT4 agg (relu,+b4) + fused bn stats =====
    node_agg_f32s<<<gAgg2, TB, 0, stream>>>(off, ssorted, bufB, esB, edB, b4, bufAf, sums32);
    bn_relu_attn<<<N / 8, TB, 0, stream>>>(bufAf, sums32, g4, be4, atl, bufB, esA, edA);

    // ===== fused: agg5 -> q -> out = q@W5 + b5 =====
    agg_mm128<<<gAgg2, TB, 0, stream>>>(off, ssorted, bufB, esA, edA, W5, b5, out);
}